// Round 11
// baseline (373.122 us; speedup 1.0000x reference)
//
#include <hip/hip_runtime.h>

#define Sn 1024
#define Dn 64
#define PH_LD 1032   // ushorts/row: 516 dw ≡ 4 (mod 32)
#define K_LD 72
#define V_LD 72

typedef short v8s __attribute__((ext_vector_type(8)));
typedef unsigned short v8u __attribute__((ext_vector_type(8)));
typedef float v4f __attribute__((ext_vector_type(4)));
typedef int   v4i __attribute__((ext_vector_type(4)));

#define LGKM0()  asm volatile("s_waitcnt lgkmcnt(0)" ::: "memory")
#define SBAR()   do { asm volatile("" ::: "memory"); __builtin_amdgcn_s_barrier(); \
                      __builtin_amdgcn_sched_barrier(0); } while (0)

__device__ __forceinline__ unsigned short f2bf(float x) {
    union { float f; unsigned u; } v; v.f = x;
    return (unsigned short)((v.u + 0x7FFFu + ((v.u >> 16) & 1u)) >> 16);
}
__device__ __forceinline__ float bf2f(unsigned short h) {
    union { float f; unsigned u; } v; v.u = ((unsigned)h) << 16;
    return v.f;
}
__device__ __forceinline__ void split2(float x, unsigned short& h, unsigned short& l) {
    unsigned short hs = f2bf(x);
    h = hs; l = f2bf(x - bf2f(hs));
}

// ---- prep: K -> fragment-interleaved bf16 hi/lo ----
// KF[bh][kt][w][f][lane][8]; fused fragment load = 64 lanes x 16B contiguous.
__global__ __launch_bounds__(256) void prep_kf(const float* __restrict__ K,
    unsigned short* __restrict__ KF)
{
    const int bh = blockIdx.x >> 4, kt = blockIdx.x & 15;
    const int t = threadIdx.x;
    const int w = t >> 6, lane = t & 63;
    const int fr = lane & 15, g = lane >> 4;
    const float* src = K + (((size_t)(bh << 10) + (kt << 6) + (w << 4) + fr) << 6);
    const v4f a0 = __builtin_nontemporal_load((const v4f*)(src + (g << 3)));
    const v4f a1 = __builtin_nontemporal_load((const v4f*)(src + (g << 3) + 4));
    const v4f b0 = __builtin_nontemporal_load((const v4f*)(src + 32 + (g << 3)));
    const v4f b1 = __builtin_nontemporal_load((const v4f*)(src + 32 + (g << 3) + 4));
    v8u h0, h1, l0, l1;
    #pragma unroll
    for (int j = 0; j < 4; ++j) {
        unsigned short hh, ll;
        split2(a0[j], hh, ll); h0[j] = hh;     l0[j] = ll;
        split2(a1[j], hh, ll); h0[4 + j] = hh; l0[4 + j] = ll;
        split2(b0[j], hh, ll); h1[j] = hh;     l1[j] = ll;
        split2(b1[j], hh, ll); h1[4 + j] = hh; l1[4 + j] = ll;
    }
    unsigned short* dst = KF + ((size_t)bh << 17) + ((size_t)((kt << 2) + w) << 11) + (lane << 3);
    *(v8u*)(dst)        = h0;
    *(v8u*)(dst + 512)  = h1;
    *(v8u*)(dst + 1024) = l0;
    *(v8u*)(dst + 1536) = l1;
}

// ---- prep: V -> fragment-interleaved V^T bf16 ----
__global__ __launch_bounds__(256) void prep_vf(const float* __restrict__ V,
    unsigned short* __restrict__ VF)
{
    __shared__ float Ts[64][65];
    const int bh = blockIdx.x >> 4, kt = blockIdx.x & 15;
    const int t = threadIdx.x;
    {
        const int r = t >> 2, cs = (t & 3) << 4;
        const float* src = V + ((size_t)bh * Sn + (kt << 6) + r) * Dn + cs;
        const v4f a = __builtin_nontemporal_load((const v4f*)src);
        const v4f b = __builtin_nontemporal_load((const v4f*)src + 1);
        const v4f c = __builtin_nontemporal_load((const v4f*)src + 2);
        const v4f d = __builtin_nontemporal_load((const v4f*)src + 3);
        #pragma unroll
        for (int j = 0; j < 4; ++j) {
            Ts[r][cs + j]      = a[j];
            Ts[r][cs + 4 + j]  = b[j];
            Ts[r][cs + 8 + j]  = c[j];
            Ts[r][cs + 12 + j] = d[j];
        }
    }
    __syncthreads();
    {
        const int w = t >> 6, lane = t & 63;
        const int fr = lane & 15, g = lane >> 4;
        const int d = (w << 4) + fr;
        unsigned short* dst = VF + ((size_t)bh << 16) + ((size_t)((kt << 2) + w) << 10) + (lane << 3);
        v8u o0, o1;
        #pragma unroll
        for (int j = 0; j < 8; ++j) o0[j] = f2bf(Ts[(g << 3) + j][d]);
        #pragma unroll
        for (int j = 0; j < 8; ++j) o1[j] = f2bf(Ts[32 + (g << 3) + j][d]);
        *(v8u*)dst         = o0;
        *(v8u*)(dst + 512) = o1;
    }
}

// ---- fused attention: coalesced frags, raw mask (8-deep prefetch), no prep_m ----
// Block: 16 q-rows, 4 waves, 4 blocks/CU (LDS = Ph only, 33 KB). Barrier-free
// phases; mask int4 read directly from HBM with depth-8 ring (static indices).
__global__ __launch_bounds__(256, 4) void fused_attn_c(
    const unsigned short* __restrict__ KFG, const unsigned short* __restrict__ VFG,
    const float* __restrict__ Q, const int* __restrict__ M,
    float* __restrict__ attnO, float* __restrict__ ctxO)
{
    __shared__ unsigned short Ph[16][PH_LD];
    __shared__ float rsumW[4][16];
    __shared__ float invL[16];

    const int tid  = threadIdx.x;
    const int lane = tid & 63;
    const int w    = tid >> 6;
    const int fr   = lane & 15;
    const int g    = lane >> 4;

    // bijective XCD swizzle: all 64 q-blocks of one bh on one XCD
    const int swz = ((blockIdx.x & 7) << 10) + (blockIdx.x >> 3);
    const int bh = swz >> 6;
    const int q0 = (swz & 63) << 4;

    const float* Qb = Q + (size_t)bh * Sn * Dn + (size_t)q0 * Dn;
    float*       Ab = attnO + (size_t)bh * Sn * Sn + (size_t)q0 * Sn;
    float*       Cb = ctxO  + (size_t)bh * Sn * Dn + (size_t)q0 * Dn;
    const unsigned short* KFb = KFG + ((size_t)bh << 17);
    const unsigned short* VFb = VFG + ((size_t)bh << 16);
    // per-lane raw mask: row q0+fr, cols kt*64 + w*16 + g*4 (int4)
    const int* mp = M + (size_t)bh * Sn * Sn + (size_t)(q0 + fr) * Sn + (w << 4) + (g << 2);

    // Q B-fragments (once per block)
    v8s qh0, qh1, ql0, ql1;
    {
        const float* qp = Qb + fr * Dn + (g << 3);
        float x0[8], x1[8];
        *(v4f*)&x0[0] = *(const v4f*)qp;
        *(v4f*)&x0[4] = *(const v4f*)(qp + 4);
        *(v4f*)&x1[0] = *(const v4f*)(qp + 32);
        *(v4f*)&x1[4] = *(const v4f*)(qp + 36);
        #pragma unroll
        for (int i = 0; i < 8; ++i) {
            unsigned short hh, ll;
            split2(x0[i], hh, ll); qh0[i] = (short)hh; ql0[i] = (short)ll;
            split2(x1[i], hh, ll); qh1[i] = (short)hh; ql1[i] = (short)ll;
        }
    }

#define LDK(kt, h0, h1, l0, l1) do {                                               \
        const unsigned short* _p = KFb + ((size_t)(((kt) << 2) + w) << 11) + (lane << 3); \
        h0 = *(const v8s*)_p;          h1 = *(const v8s*)(_p + 512);               \
        l0 = *(const v8s*)(_p + 1024); l1 = *(const v8s*)(_p + 1536);              \
    } while (0)

#define STEPA(h0, h1, l0, l1, mv, kt) do {                                         \
        v4f acc = {0.f, 0.f, 0.f, 0.f};                                            \
        __builtin_amdgcn_s_setprio(1);                                             \
        acc = __builtin_amdgcn_mfma_f32_16x16x32_bf16(h0, qh0, acc, 0, 0, 0);      \
        acc = __builtin_amdgcn_mfma_f32_16x16x32_bf16(h1, qh1, acc, 0, 0, 0);      \
        acc = __builtin_amdgcn_mfma_f32_16x16x32_bf16(l0, qh0, acc, 0, 0, 0);      \
        acc = __builtin_amdgcn_mfma_f32_16x16x32_bf16(l1, qh1, acc, 0, 0, 0);      \
        acc = __builtin_amdgcn_mfma_f32_16x16x32_bf16(h0, ql0, acc, 0, 0, 0);      \
        acc = __builtin_amdgcn_mfma_f32_16x16x32_bf16(h1, ql1, acc, 0, 0, 0);      \
        __builtin_amdgcn_s_setprio(0);                                             \
        const float e0 = (mv)[0] ? 1.0f : __expf(acc[0]);                          \
        const float e1 = (mv)[1] ? 1.0f : __expf(acc[1]);                          \
        const float e2 = (mv)[2] ? 1.0f : __expf(acc[2]);                          \
        const float e3 = (mv)[3] ? 1.0f : __expf(acc[3]);                          \
        rs += (e0 + e1) + (e2 + e3);                                               \
        ushort4 pk;                                                                \
        pk.x = f2bf(e0); pk.y = f2bf(e1); pk.z = f2bf(e2); pk.w = f2bf(e3);        \
        *(ushort4*)&Ph[fr][((kt) << 6) + (w << 4) + (g << 2)] = pk;                \
    } while (0)

    float rs = 0.f;

    // ---- Phase A: barrier-free; K depth-2 slots, mask depth-8 ring ----
    {
        v8s h0[2], h1[2], l0[2], l1[2];
        v4i mk[8];
        LDK(0, h0[0], h1[0], l0[0], l1[0]);
        LDK(1, h0[1], h1[1], l0[1], l1[1]);
        #pragma unroll
        for (int s = 0; s < 8; ++s) mk[s] = *(const v4i*)(mp + (s << 6));
        #pragma unroll
        for (int kt = 0; kt < 16; ++kt) {
            STEPA(h0[kt & 1], h1[kt & 1], l0[kt & 1], l1[kt & 1], mk[kt & 7], kt);
            if (kt + 2 < 16) LDK(kt + 2, h0[kt & 1], h1[kt & 1], l0[kt & 1], l1[kt & 1]);
            if (kt + 8 < 16) mk[kt & 7] = *(const v4i*)(mp + ((kt + 8) << 6));
        }
    }

    // ---- row-sum reduce (only barriers; raw, no vmcnt drain) ----
    rs += __shfl_xor(rs, 16);
    rs += __shfl_xor(rs, 32);
    if (g == 0) rsumW[w][fr] = rs;
    __builtin_amdgcn_sched_barrier(0);
    LGKM0();
    SBAR();
    if (tid < 16) {
        const float s = rsumW[0][tid] + rsumW[1][tid] + rsumW[2][tid] + rsumW[3][tid];
        invL[tid] = 1.0f / s;
    }
    __builtin_amdgcn_sched_barrier(0);
    LGKM0();
    SBAR();

#define LDV(kt, v0, v1) do {                                                       \
        const unsigned short* _p = VFb + ((size_t)(((kt) << 2) + w) << 10) + (lane << 3); \
        v0 = *(const v8s*)_p;  v1 = *(const v8s*)(_p + 512);                       \
    } while (0)

#define STEPB(v0, v1, kt) do {                                                     \
        const v8s a0 = *(const v8s*)&Ph[fr][((kt) << 6) + (g << 3)];               \
        const v8s a1 = *(const v8s*)&Ph[fr][((kt) << 6) + 32 + (g << 3)];          \
        __builtin_amdgcn_s_setprio(1);                                             \
        accp = __builtin_amdgcn_mfma_f32_16x16x32_bf16(a0, v0, accp, 0, 0, 0);     \
        accp = __builtin_amdgcn_mfma_f32_16x16x32_bf16(a1, v1, accp, 0, 0, 0);     \
        __builtin_amdgcn_s_setprio(0);                                             \
    } while (0)

    // Issue first V frag loads BEFORE the attn store burst (in-order vmcnt:
    // loads before stores -> Phase B never waits on the store stream).
    v8s va0, va1, vb0, vb1;
    LDV(0, va0, va1);
    LDV(1, vb0, vb1);

    // ---- write normalized attn (NT burst drains under Phase B) ----
    {
        const int qq = tid >> 4, ii = tid & 15;
        const float inv = invL[qq];
        float* arow = Ab + (size_t)qq * Sn;
        #pragma unroll
        for (int c = 0; c < 16; ++c) {
            const int k0 = (c << 6) + (ii << 2);
            const ushort4 p = *(const ushort4*)&Ph[qq][k0];
            v4f o;
            o[0] = bf2f(p.x) * inv; o[1] = bf2f(p.y) * inv;
            o[2] = bf2f(p.z) * inv; o[3] = bf2f(p.w) * inv;
            __builtin_nontemporal_store(o, (v4f*)(arow + k0));
        }
    }

    // ---- Phase B: barrier-free, coalesced V frags ----
    const int dcol = (w << 4) + fr;
    v4f accp = {0.f, 0.f, 0.f, 0.f};
    for (int kt = 0; kt < 16; kt += 2) {
        const int k2 = (kt + 2 < 16) ? kt + 2 : kt;
        const int k3 = (kt + 3 < 16) ? kt + 3 : kt;
        v8s vc0, vc1, vd0, vd1;
        LDV(k2, vc0, vc1);
        LDV(k3, vd0, vd1);
        STEPB(va0, va1, kt);
        STEPB(vb0, vb1, kt + 1);
        va0 = vc0; va1 = vc1;
        vb0 = vd0; vb1 = vd1;
    }
    #pragma unroll
    for (int r = 0; r < 4; ++r) {
        const int q = (g << 2) + r;
        __builtin_nontemporal_store(accp[r] * invL[q], &Cb[(size_t)q * Dn + dcol]);
    }
#undef LDK
#undef STEPA
#undef LDV
#undef STEPB
}

// ---------------- fallback (round-3 kernel, in-kernel split) ----------------
__global__ __launch_bounds__(256, 3) void fused_attn_fb(
    const float* __restrict__ Q, const float* __restrict__ K,
    const float* __restrict__ V, const int* __restrict__ M,
    float* __restrict__ attnO, float* __restrict__ ctxO)
{
    __shared__ unsigned short Ph[16][1048];
    __shared__ __align__(16) unsigned short Kraw[2 * 64 * K_LD];
    __shared__ float rsumW[4][16];
    __shared__ float invL[16];

    unsigned short (*Khi)[K_LD] = (unsigned short (*)[K_LD])Kraw;
    unsigned short (*Klo)[K_LD] = (unsigned short (*)[K_LD])(Kraw + 64 * K_LD);
    unsigned short (*Vt)[V_LD]  = (unsigned short (*)[V_LD])Kraw;

    const int tid  = threadIdx.x;
    const int lane = tid & 63;
    const int w    = tid >> 6;
    const int fr   = lane & 15;
    const int g    = lane >> 4;

    const int bh = blockIdx.x >> 6;
    const int q0 = (blockIdx.x & 63) << 4;

    const float* Qb = Q + (size_t)bh * Sn * Dn + (size_t)q0 * Dn;
    const float* Kb = K + (size_t)bh * Sn * Dn;
    const float* Vb = V + (size_t)bh * Sn * Dn;
    const int*   Mb = M + (size_t)bh * Sn * Sn + (size_t)q0 * Sn;
    float*       Ab = attnO + (size_t)bh * Sn * Sn + (size_t)q0 * Sn;
    float*       Cb = ctxO  + (size_t)bh * Sn * Dn + (size_t)q0 * Dn;

    v8s qh0, qh1, ql0, ql1;
    {
        const float* qp = Qb + fr * Dn + (g << 3);
        float x0[8], x1[8];
        *(v4f*)&x0[0] = *(const v4f*)qp;
        *(v4f*)&x0[4] = *(const v4f*)(qp + 4);
        *(v4f*)&x1[0] = *(const v4f*)(qp + 32);
        *(v4f*)&x1[4] = *(const v4f*)(qp + 36);
        #pragma unroll
        for (int i = 0; i < 8; ++i) {
            unsigned short hh, ll;
            split2(x0[i], hh, ll); qh0[i] = (short)hh; ql0[i] = (short)ll;
            split2(x1[i], hh, ll); qh1[i] = (short)hh; ql1[i] = (short)ll;
        }
    }

    const int srow = tid >> 4;
    const int sc4  = (tid & 15) << 2;

    const int* mp = Mb + (size_t)fr * Sn + (w << 4) + (g << 2);
    v4i mv = *(const v4i*)mp;

    v4f ka[4];
    #pragma unroll
    for (int i = 0; i < 4; ++i)
        ka[i] = *(const v4f*)(Kb + (size_t)(srow + (i << 4)) * Dn + sc4);

    float rs = 0.f;

    for (int kt = 0; kt < 16; ++kt) {
        __syncthreads();
        v4f kb[4];
        if (kt < 15) {
            const float* kn = Kb + (size_t)((kt + 1) << 6) * Dn;
            #pragma unroll
            for (int i = 0; i < 4; ++i)
                kb[i] = *(const v4f*)(kn + (size_t)(srow + (i << 4)) * Dn + sc4);
        }
        v4i mnext = mv;
        if (kt < 15) mnext = *(const v4i*)(mp + ((kt + 1) << 6));

        #pragma unroll
        for (int i = 0; i < 4; ++i) {
            const int row = srow + (i << 4);
            ushort4 hv, lv;
            split2(ka[i][0], hv.x, lv.x); split2(ka[i][1], hv.y, lv.y);
            split2(ka[i][2], hv.z, lv.z); split2(ka[i][3], hv.w, lv.w);
            *(ushort4*)&Khi[row][sc4] = hv;
            *(ushort4*)&Klo[row][sc4] = lv;
        }
        __syncthreads();

        const int krow = (w << 4) + fr;
        const v8s kh0 = *(const v8s*)&Khi[krow][(g << 3)];
        const v8s kh1 = *(const v8s*)&Khi[krow][32 + (g << 3)];
        const v8s kl0 = *(const v8s*)&Klo[krow][(g << 3)];
        const v8s kl1 = *(const v8s*)&Klo[krow][32 + (g << 3)];

        v4f acc = {0.f, 0.f, 0.f, 0.f};
        acc = __builtin_amdgcn_mfma_f32_16x16x32_bf16(kh0, qh0, acc, 0, 0, 0);
        acc = __builtin_amdgcn_mfma_f32_16x16x32_bf16(kh1, qh1, acc, 0, 0, 0);
        acc = __builtin_amdgcn_mfma_f32_16x16x32_bf16(kl0, qh0, acc, 0, 0, 0);
        acc = __builtin_amdgcn_mfma_f32_16x16x32_bf16(kl1, qh1, acc, 0, 0, 0);
        acc = __builtin_amdgcn_mfma_f32_16x16x32_bf16(kh0, ql0, acc, 0, 0, 0);
        acc = __builtin_amdgcn_mfma_f32_16x16x32_bf16(kh1, ql1, acc, 0, 0, 0);

        const float e0 = mv[0] ? 1.0f : __expf(acc[0]);
        const float e1 = mv[1] ? 1.0f : __expf(acc[1]);
        const float e2 = mv[2] ? 1.0f : __expf(acc[2]);
        const float e3 = mv[3] ? 1.0f : __expf(acc[3]);
        rs += (e0 + e1) + (e2 + e3);
        ushort4 pk;
        pk.x = f2bf(e0); pk.y = f2bf(e1); pk.z = f2bf(e2); pk.w = f2bf(e3);
        *(ushort4*)&Ph[fr][(kt << 6) + (w << 4) + (g << 2)] = pk;

        mv = mnext;
        #pragma unroll
        for (int i = 0; i < 4; ++i) ka[i] = kb[i];
    }

    rs += __shfl_xor(rs, 16);
    rs += __shfl_xor(rs, 32);
    if (g == 0) rsumW[w][fr] = rs;
    __syncthreads();
    if (tid < 16) {
        const float s = rsumW[0][tid] + rsumW[1][tid] + rsumW[2][tid] + rsumW[3][tid];
        invL[tid] = 1.0f / s;
    }
    __syncthreads();

    const int dcol = (w << 4) + fr;
    v4f va[4];
    #pragma unroll
    for (int i = 0; i < 4; ++i)
        va[i] = *(const v4f*)(Vb + (size_t)(srow + (i << 4)) * Dn + sc4);

    v4f accp = {0.f, 0.f, 0.f, 0.f};
    for (int kt = 0; kt < 16; ++kt) {
        __syncthreads();
        v4f vb[4];
        if (kt < 15) {
            const float* vn = Vb + (size_t)((kt + 1) << 6) * Dn;
            #pragma unroll
            for (int i = 0; i < 4; ++i)
                vb[i] = *(const v4f*)(vn + (size_t)(srow + (i << 4)) * Dn + sc4);
        }
        #pragma unroll
        for (int i = 0; i < 4; ++i) {
            const int row = srow + (i << 4);
            Vt[sc4 + 0][row] = f2bf(va[i][0]);
            Vt[sc4 + 1][row] = f2bf(va[i][1]);
            Vt[sc4 + 2][row] = f2bf(va[i][2]);
            Vt[sc4 + 3][row] = f2bf(va[i][3]);
        }
        __syncthreads();

        #pragma unroll
        for (int c = 0; c < 2; ++c) {
            const int kc = (kt << 6) + (c << 5);
            const v8s a = *(const v8s*)&Ph[fr][kc + (g << 3)];
            const v8s b = *(const v8s*)&Vt[dcol][(c << 5) + (g << 3)];
            accp = __builtin_amdgcn_mfma_f32_16x16x32_bf16(a, b, accp, 0, 0, 0);
        }
        #pragma unroll
        for (int i = 0; i < 4; ++i) va[i] = vb[i];
    }
    #pragma unroll
    for (int r = 0; r < 4; ++r) {
        const int q = (g << 2) + r;
        Cb[(size_t)q * Dn + dcol] = accp[r] * invL[q];
    }

    {
        const int qq = tid >> 4, ii = tid & 15;
        const float inv = invL[qq];
        float* arow = Ab + (size_t)qq * Sn;
        #pragma unroll
        for (int c = 0; c < 16; ++c) {
            const int k0 = (c << 6) + (ii << 2);
            const ushort4 p = *(const ushort4*)&Ph[qq][k0];
            v4f o;
            o[0] = bf2f(p.x) * inv; o[1] = bf2f(p.y) * inv;
            o[2] = bf2f(p.z) * inv; o[3] = bf2f(p.w) * inv;
            *(v4f*)(arow + k0) = o;
        }
    }
}

extern "C" void kernel_launch(void* const* d_in, const int* in_sizes, int n_in,
                              void* d_out, int out_size, void* d_ws, size_t ws_size,
                              hipStream_t stream) {
    const float* Q    = (const float*)d_in[0];
    const float* K    = (const float*)d_in[1];
    const float* V    = (const float*)d_in[2];
    const int*   mask = (const int*)d_in[3];

    float* ctx  = (float*)d_out;                           // (B,H,S,D)
    float* attn = (float*)d_out + (size_t)128 * Sn * Dn;   // (B,H,S,S)

    const size_t NELEM = (size_t)128 * Sn * Dn;            // 8,388,608
    const size_t NEED  = NELEM * 6;                        // KF 33.5MB + VF 16.8MB

    if (ws_size >= NEED) {
        unsigned short* KF = (unsigned short*)d_ws;        // hi/lo frag-interleaved
        unsigned short* VF = KF + NELEM * 2;               // V^T frag-interleaved
        prep_kf<<<2048, 256, 0, stream>>>(K, KF);
        prep_vf<<<2048, 256, 0, stream>>>(V, VF);
        fused_attn_c<<<128 * 64, 256, 0, stream>>>(KF, VF, Q, mask, attn, ctx);
    } else {
        fused_attn_fb<<<128 * 64, 256, 0, stream>>>(Q, K, V, mask, attn, ctx);
    }
}

// Round 12
// 356.466 us; speedup vs baseline: 1.0467x; 1.0467x over previous
//
#include <hip/hip_runtime.h>

#define Sn 1024
#define Dn 64
#define PH_LD 1032   // ushorts/row: 516 dw ≡ 4 (mod 32)
#define K_LD 72
#define V_LD 72

typedef short v8s __attribute__((ext_vector_type(8)));
typedef unsigned short v8u __attribute__((ext_vector_type(8)));
typedef float v4f __attribute__((ext_vector_type(4)));
typedef int   v4i __attribute__((ext_vector_type(4)));

#define LGKM0()  asm volatile("s_waitcnt lgkmcnt(0)" ::: "memory")
#define SBAR()   do { asm volatile("" ::: "memory"); __builtin_amdgcn_s_barrier(); \
                      __builtin_amdgcn_sched_barrier(0); } while (0)

__device__ __forceinline__ unsigned short f2bf(float x) {
    union { float f; unsigned u; } v; v.f = x;
    return (unsigned short)((v.u + 0x7FFFu + ((v.u >> 16) & 1u)) >> 16);
}
__device__ __forceinline__ float bf2f(unsigned short h) {
    union { float f; unsigned u; } v; v.u = ((unsigned)h) << 16;
    return v.f;
}
__device__ __forceinline__ void split2(float x, unsigned short& h, unsigned short& l) {
    unsigned short hs = f2bf(x);
    h = hs; l = f2bf(x - bf2f(hs));
}

// ---- prep: K -> fragment-interleaved bf16 hi/lo ----
// KF[bh][kt][w][f][lane][8]; fused fragment load = 64 lanes x 16B contiguous.
__global__ __launch_bounds__(256) void prep_kf(const float* __restrict__ K,
    unsigned short* __restrict__ KF)
{
    const int bh = blockIdx.x >> 4, kt = blockIdx.x & 15;
    const int t = threadIdx.x;
    const int w = t >> 6, lane = t & 63;
    const int fr = lane & 15, g = lane >> 4;
    const float* src = K + (((size_t)(bh << 10) + (kt << 6) + (w << 4) + fr) << 6);
    const v4f a0 = __builtin_nontemporal_load((const v4f*)(src + (g << 3)));
    const v4f a1 = __builtin_nontemporal_load((const v4f*)(src + (g << 3) + 4));
    const v4f b0 = __builtin_nontemporal_load((const v4f*)(src + 32 + (g << 3)));
    const v4f b1 = __builtin_nontemporal_load((const v4f*)(src + 32 + (g << 3) + 4));
    v8u h0, h1, l0, l1;
    #pragma unroll
    for (int j = 0; j < 4; ++j) {
        unsigned short hh, ll;
        split2(a0[j], hh, ll); h0[j] = hh;     l0[j] = ll;
        split2(a1[j], hh, ll); h0[4 + j] = hh; l0[4 + j] = ll;
        split2(b0[j], hh, ll); h1[j] = hh;     l1[j] = ll;
        split2(b1[j], hh, ll); h1[4 + j] = hh; l1[4 + j] = ll;
    }
    unsigned short* dst = KF + ((size_t)bh << 17) + ((size_t)((kt << 2) + w) << 11) + (lane << 3);
    *(v8u*)(dst)        = h0;
    *(v8u*)(dst + 512)  = h1;
    *(v8u*)(dst + 1024) = l0;
    *(v8u*)(dst + 1536) = l1;
}

// ---- prep: V -> fragment-interleaved V^T bf16 ----
__global__ __launch_bounds__(256) void prep_vf(const float* __restrict__ V,
    unsigned short* __restrict__ VF)
{
    __shared__ float Ts[64][65];
    const int bh = blockIdx.x >> 4, kt = blockIdx.x & 15;
    const int t = threadIdx.x;
    {
        const int r = t >> 2, cs = (t & 3) << 4;
        const float* src = V + ((size_t)bh * Sn + (kt << 6) + r) * Dn + cs;
        const v4f a = __builtin_nontemporal_load((const v4f*)src);
        const v4f b = __builtin_nontemporal_load((const v4f*)src + 1);
        const v4f c = __builtin_nontemporal_load((const v4f*)src + 2);
        const v4f d = __builtin_nontemporal_load((const v4f*)src + 3);
        #pragma unroll
        for (int j = 0; j < 4; ++j) {
            Ts[r][cs + j]      = a[j];
            Ts[r][cs + 4 + j]  = b[j];
            Ts[r][cs + 8 + j]  = c[j];
            Ts[r][cs + 12 + j] = d[j];
        }
    }
    __syncthreads();
    {
        const int w = t >> 6, lane = t & 63;
        const int fr = lane & 15, g = lane >> 4;
        const int d = (w << 4) + fr;
        unsigned short* dst = VF + ((size_t)bh << 16) + ((size_t)((kt << 2) + w) << 10) + (lane << 3);
        v8u o0, o1;
        #pragma unroll
        for (int j = 0; j < 8; ++j) o0[j] = f2bf(Ts[(g << 3) + j][d]);
        #pragma unroll
        for (int j = 0; j < 8; ++j) o1[j] = f2bf(Ts[32 + (g << 3) + j][d]);
        *(v8u*)dst         = o0;
        *(v8u*)(dst + 512) = o1;
    }
}

// ---- fused attention: coalesced frags; raw mask read ALL-UPFRONT ----
// Block: 16 q-rows, 4 waves, 4 blocks/CU (LDS = Ph only, 33 KB).
// All 16 mask int4 NT-loads issued in the prologue BEFORE any K load: the
// in-order vm queue then charges the ~900cy HBM latency ONCE per block
// (hidden by the 3 other resident blocks), and the steady-state loop waits
// only on L2 K-fragment loads. This removes the separate prep_m pass.
__global__ __launch_bounds__(256, 4) void fused_attn_c2(
    const unsigned short* __restrict__ KFG, const unsigned short* __restrict__ VFG,
    const float* __restrict__ Q, const int* __restrict__ M,
    float* __restrict__ attnO, float* __restrict__ ctxO)
{
    __shared__ unsigned short Ph[16][PH_LD];
    __shared__ float rsumW[4][16];
    __shared__ float invL[16];

    const int tid  = threadIdx.x;
    const int lane = tid & 63;
    const int w    = tid >> 6;
    const int fr   = lane & 15;
    const int g    = lane >> 4;

    // bijective XCD swizzle: all 64 q-blocks of one bh on one XCD
    const int swz = ((blockIdx.x & 7) << 10) + (blockIdx.x >> 3);
    const int bh = swz >> 6;
    const int q0 = (swz & 63) << 4;

    const float* Qb = Q + (size_t)bh * Sn * Dn + (size_t)q0 * Dn;
    float*       Ab = attnO + (size_t)bh * Sn * Sn + (size_t)q0 * Sn;
    float*       Cb = ctxO  + (size_t)bh * Sn * Dn + (size_t)q0 * Dn;
    const unsigned short* KFb = KFG + ((size_t)bh << 17);
    const unsigned short* VFb = VFG + ((size_t)bh << 16);
    // per-lane raw mask: row q0+fr, cols kt*64 + w*16 + g*4 (int4)
    const int* mp = M + (size_t)bh * Sn * Sn + (size_t)(q0 + fr) * Sn + (w << 4) + (g << 2);

    // ---- ALL mask loads first (NT, single-use stream) ----
    v4i mk[16];
    #pragma unroll
    for (int s = 0; s < 16; ++s)
        mk[s] = __builtin_nontemporal_load((const v4i*)(mp + (s << 6)));

    // Q B-fragments (after masks: Q loads sit behind masks in the queue, fine)
    v8s qh0, qh1, ql0, ql1;
    {
        const float* qp = Qb + fr * Dn + (g << 3);
        float x0[8], x1[8];
        *(v4f*)&x0[0] = *(const v4f*)qp;
        *(v4f*)&x0[4] = *(const v4f*)(qp + 4);
        *(v4f*)&x1[0] = *(const v4f*)(qp + 32);
        *(v4f*)&x1[4] = *(const v4f*)(qp + 36);
        #pragma unroll
        for (int i = 0; i < 8; ++i) {
            unsigned short hh, ll;
            split2(x0[i], hh, ll); qh0[i] = (short)hh; ql0[i] = (short)ll;
            split2(x1[i], hh, ll); qh1[i] = (short)hh; ql1[i] = (short)ll;
        }
    }

#define LDK(kt, h0, h1, l0, l1) do {                                               \
        const unsigned short* _p = KFb + ((size_t)(((kt) << 2) + w) << 11) + (lane << 3); \
        h0 = *(const v8s*)_p;          h1 = *(const v8s*)(_p + 512);               \
        l0 = *(const v8s*)(_p + 1024); l1 = *(const v8s*)(_p + 1536);              \
    } while (0)

#define STEPA(h0, h1, l0, l1, mv, kt) do {                                         \
        v4f acc = {0.f, 0.f, 0.f, 0.f};                                            \
        __builtin_amdgcn_s_setprio(1);                                             \
        acc = __builtin_amdgcn_mfma_f32_16x16x32_bf16(h0, qh0, acc, 0, 0, 0);      \
        acc = __builtin_amdgcn_mfma_f32_16x16x32_bf16(h1, qh1, acc, 0, 0, 0);      \
        acc = __builtin_amdgcn_mfma_f32_16x16x32_bf16(l0, qh0, acc, 0, 0, 0);      \
        acc = __builtin_amdgcn_mfma_f32_16x16x32_bf16(l1, qh1, acc, 0, 0, 0);      \
        acc = __builtin_amdgcn_mfma_f32_16x16x32_bf16(h0, ql0, acc, 0, 0, 0);      \
        acc = __builtin_amdgcn_mfma_f32_16x16x32_bf16(h1, ql1, acc, 0, 0, 0);      \
        __builtin_amdgcn_s_setprio(0);                                             \
        const float e0 = (mv)[0] ? 1.0f : __expf(acc[0]);                          \
        const float e1 = (mv)[1] ? 1.0f : __expf(acc[1]);                          \
        const float e2 = (mv)[2] ? 1.0f : __expf(acc[2]);                          \
        const float e3 = (mv)[3] ? 1.0f : __expf(acc[3]);                          \
        rs += (e0 + e1) + (e2 + e3);                                               \
        ushort4 pk;                                                                \
        pk.x = f2bf(e0); pk.y = f2bf(e1); pk.z = f2bf(e2); pk.w = f2bf(e3);        \
        *(ushort4*)&Ph[fr][((kt) << 6) + (w << 4) + (g << 2)] = pk;                \
    } while (0)

    float rs = 0.f;

    // ---- Phase A: barrier-free; K depth-2 slots; masks already in regs ----
    {
        v8s h0[2], h1[2], l0[2], l1[2];
        LDK(0, h0[0], h1[0], l0[0], l1[0]);
        LDK(1, h0[1], h1[1], l0[1], l1[1]);
        #pragma unroll
        for (int kt = 0; kt < 16; ++kt) {
            STEPA(h0[kt & 1], h1[kt & 1], l0[kt & 1], l1[kt & 1], mk[kt], kt);
            if (kt + 2 < 16) LDK(kt + 2, h0[kt & 1], h1[kt & 1], l0[kt & 1], l1[kt & 1]);
        }
    }

    // ---- row-sum reduce (only barriers; raw, no vmcnt drain) ----
    rs += __shfl_xor(rs, 16);
    rs += __shfl_xor(rs, 32);
    if (g == 0) rsumW[w][fr] = rs;
    __builtin_amdgcn_sched_barrier(0);
    LGKM0();
    SBAR();
    if (tid < 16) {
        const float s = rsumW[0][tid] + rsumW[1][tid] + rsumW[2][tid] + rsumW[3][tid];
        invL[tid] = 1.0f / s;
    }
    __builtin_amdgcn_sched_barrier(0);
    LGKM0();
    SBAR();

#define LDV(kt, v0, v1) do {                                                       \
        const unsigned short* _p = VFb + ((size_t)(((kt) << 2) + w) << 10) + (lane << 3); \
        v0 = *(const v8s*)_p;  v1 = *(const v8s*)(_p + 512);                       \
    } while (0)

#define STEPB(v0, v1, kt) do {                                                     \
        const v8s a0 = *(const v8s*)&Ph[fr][((kt) << 6) + (g << 3)];               \
        const v8s a1 = *(const v8s*)&Ph[fr][((kt) << 6) + 32 + (g << 3)];          \
        __builtin_amdgcn_s_setprio(1);                                             \
        accp = __builtin_amdgcn_mfma_f32_16x16x32_bf16(a0, v0, accp, 0, 0, 0);     \
        accp = __builtin_amdgcn_mfma_f32_16x16x32_bf16(a1, v1, accp, 0, 0, 0);     \
        __builtin_amdgcn_s_setprio(0);                                             \
    } while (0)

    // Issue first V frag loads BEFORE the attn store burst (in-order vmcnt:
    // loads before stores -> Phase B never waits on the store stream).
    v8s va0, va1, vb0, vb1;
    LDV(0, va0, va1);
    LDV(1, vb0, vb1);

    // ---- write normalized attn (NT burst drains under Phase B) ----
    {
        const int qq = tid >> 4, ii = tid & 15;
        const float inv = invL[qq];
        float* arow = Ab + (size_t)qq * Sn;
        #pragma unroll
        for (int c = 0; c < 16; ++c) {
            const int k0 = (c << 6) + (ii << 2);
            const ushort4 p = *(const ushort4*)&Ph[qq][k0];
            v4f o;
            o[0] = bf2f(p.x) * inv; o[1] = bf2f(p.y) * inv;
            o[2] = bf2f(p.z) * inv; o[3] = bf2f(p.w) * inv;
            __builtin_nontemporal_store(o, (v4f*)(arow + k0));
        }
    }

    // ---- Phase B: barrier-free, coalesced V frags ----
    const int dcol = (w << 4) + fr;
    v4f accp = {0.f, 0.f, 0.f, 0.f};
    for (int kt = 0; kt < 16; kt += 2) {
        const int k2 = (kt + 2 < 16) ? kt + 2 : kt;
        const int k3 = (kt + 3 < 16) ? kt + 3 : kt;
        v8s vc0, vc1, vd0, vd1;
        LDV(k2, vc0, vc1);
        LDV(k3, vd0, vd1);
        STEPB(va0, va1, kt);
        STEPB(vb0, vb1, kt + 1);
        va0 = vc0; va1 = vc1;
        vb0 = vd0; vb1 = vd1;
    }
    #pragma unroll
    for (int r = 0; r < 4; ++r) {
        const int q = (g << 2) + r;
        __builtin_nontemporal_store(accp[r] * invL[q], &Cb[(size_t)q * Dn + dcol]);
    }
#undef LDK
#undef STEPA
#undef LDV
#undef STEPB
}

// ---------------- fallback (round-3 kernel, in-kernel split) ----------------
__global__ __launch_bounds__(256, 3) void fused_attn_fb(
    const float* __restrict__ Q, const float* __restrict__ K,
    const float* __restrict__ V, const int* __restrict__ M,
    float* __restrict__ attnO, float* __restrict__ ctxO)
{
    __shared__ unsigned short Ph[16][1048];
    __shared__ __align__(16) unsigned short Kraw[2 * 64 * K_LD];
    __shared__ float rsumW[4][16];
    __shared__ float invL[16];

    unsigned short (*Khi)[K_LD] = (unsigned short (*)[K_LD])Kraw;
    unsigned short (*Klo)[K_LD] = (unsigned short (*)[K_LD])(Kraw + 64 * K_LD);
    unsigned short (*Vt)[V_LD]  = (unsigned short (*)[V_LD])Kraw;

    const int tid  = threadIdx.x;
    const int lane = tid & 63;
    const int w    = tid >> 6;
    const int fr   = lane & 15;
    const int g    = lane >> 4;

    const int bh = blockIdx.x >> 6;
    const int q0 = (blockIdx.x & 63) << 4;

    const float* Qb = Q + (size_t)bh * Sn * Dn + (size_t)q0 * Dn;
    const float* Kb = K + (size_t)bh * Sn * Dn;
    const float* Vb = V + (size_t)bh * Sn * Dn;
    const int*   Mb = M + (size_t)bh * Sn * Sn + (size_t)q0 * Sn;
    float*       Ab = attnO + (size_t)bh * Sn * Sn + (size_t)q0 * Sn;
    float*       Cb = ctxO  + (size_t)bh * Sn * Dn + (size_t)q0 * Dn;

    v8s qh0, qh1, ql0, ql1;
    {
        const float* qp = Qb + fr * Dn + (g << 3);
        float x0[8], x1[8];
        *(v4f*)&x0[0] = *(const v4f*)qp;
        *(v4f*)&x0[4] = *(const v4f*)(qp + 4);
        *(v4f*)&x1[0] = *(const v4f*)(qp + 32);
        *(v4f*)&x1[4] = *(const v4f*)(qp + 36);
        #pragma unroll
        for (int i = 0; i < 8; ++i) {
            unsigned short hh, ll;
            split2(x0[i], hh, ll); qh0[i] = (short)hh; ql0[i] = (short)ll;
            split2(x1[i], hh, ll); qh1[i] = (short)hh; ql1[i] = (short)ll;
        }
    }

    const int srow = tid >> 4;
    const int sc4  = (tid & 15) << 2;

    const int* mp = Mb + (size_t)fr * Sn + (w << 4) + (g << 2);
    v4i mv = *(const v4i*)mp;

    v4f ka[4];
    #pragma unroll
    for (int i = 0; i < 4; ++i)
        ka[i] = *(const v4f*)(Kb + (size_t)(srow + (i << 4)) * Dn + sc4);

    float rs = 0.f;

    for (int kt = 0; kt < 16; ++kt) {
        __syncthreads();
        v4f kb[4];
        if (kt < 15) {
            const float* kn = Kb + (size_t)((kt + 1) << 6) * Dn;
            #pragma unroll
            for (int i = 0; i < 4; ++i)
                kb[i] = *(const v4f*)(kn + (size_t)(srow + (i << 4)) * Dn + sc4);
        }
        v4i mnext = mv;
        if (kt < 15) mnext = *(const v4i*)(mp + ((kt + 1) << 6));

        #pragma unroll
        for (int i = 0; i < 4; ++i) {
            const int row = srow + (i << 4);
            ushort4 hv, lv;
            split2(ka[i][0], hv.x, lv.x); split2(ka[i][1], hv.y, lv.y);
            split2(ka[i][2], hv.z, lv.z); split2(ka[i][3], hv.w, lv.w);
            *(ushort4*)&Khi[row][sc4] = hv;
            *(ushort4*)&Klo[row][sc4] = lv;
        }
        __syncthreads();

        const int krow = (w << 4) + fr;
        const v8s kh0 = *(const v8s*)&Khi[krow][(g << 3)];
        const v8s kh1 = *(const v8s*)&Khi[krow][32 + (g << 3)];
        const v8s kl0 = *(const v8s*)&Klo[krow][(g << 3)];
        const v8s kl1 = *(const v8s*)&Klo[krow][32 + (g << 3)];

        v4f acc = {0.f, 0.f, 0.f, 0.f};
        acc = __builtin_amdgcn_mfma_f32_16x16x32_bf16(kh0, qh0, acc, 0, 0, 0);
        acc = __builtin_amdgcn_mfma_f32_16x16x32_bf16(kh1, qh1, acc, 0, 0, 0);
        acc = __builtin_amdgcn_mfma_f32_16x16x32_bf16(kl0, qh0, acc, 0, 0, 0);
        acc = __builtin_amdgcn_mfma_f32_16x16x32_bf16(kl1, qh1, acc, 0, 0, 0);
        acc = __builtin_amdgcn_mfma_f32_16x16x32_bf16(kh0, ql0, acc, 0, 0, 0);
        acc = __builtin_amdgcn_mfma_f32_16x16x32_bf16(kh1, ql1, acc, 0, 0, 0);

        const float e0 = mv[0] ? 1.0f : __expf(acc[0]);
        const float e1 = mv[1] ? 1.0f : __expf(acc[1]);
        const float e2 = mv[2] ? 1.0f : __expf(acc[2]);
        const float e3 = mv[3] ? 1.0f : __expf(acc[3]);
        rs += (e0 + e1) + (e2 + e3);
        ushort4 pk;
        pk.x = f2bf(e0); pk.y = f2bf(e1); pk.z = f2bf(e2); pk.w = f2bf(e3);
        *(ushort4*)&Ph[fr][(kt << 6) + (w << 4) + (g << 2)] = pk;

        mv = mnext;
        #pragma unroll
        for (int i = 0; i < 4; ++i) ka[i] = kb[i];
    }

    rs += __shfl_xor(rs, 16);
    rs += __shfl_xor(rs, 32);
    if (g == 0) rsumW[w][fr] = rs;
    __syncthreads();
    if (tid < 16) {
        const float s = rsumW[0][tid] + rsumW[1][tid] + rsumW[2][tid] + rsumW[3][tid];
        invL[tid] = 1.0f / s;
    }
    __syncthreads();

    const int dcol = (w << 4) + fr;
    v4f va[4];
    #pragma unroll
    for (int i = 0; i < 4; ++i)
        va[i] = *(const v4f*)(Vb + (size_t)(srow + (i << 4)) * Dn + sc4);

    v4f accp = {0.f, 0.f, 0.f, 0.f};
    for (int kt = 0; kt < 16; ++kt) {
        __syncthreads();
        v4f vb[4];
        if (kt < 15) {
            const float* vn = Vb + (size_t)((kt + 1) << 6) * Dn;
            #pragma unroll
            for (int i = 0; i < 4; ++i)
                vb[i] = *(const v4f*)(vn + (size_t)(srow + (i << 4)) * Dn + sc4);
        }
        #pragma unroll
        for (int i = 0; i < 4; ++i) {
            const int row = srow + (i << 4);
            Vt[sc4 + 0][row] = f2bf(va[i][0]);
            Vt[sc4 + 1][row] = f2bf(va[i][1]);
            Vt[sc4 + 2][row] = f2bf(va[i][2]);
            Vt[sc4 + 3][row] = f2bf(va[i][3]);
        }
        __syncthreads();

        #pragma unroll
        for (int c = 0; c < 2; ++c) {
            const int kc = (kt << 6) + (c << 5);
            const v8s a = *(const v8s*)&Ph[fr][kc + (g << 3)];
            const v8s b = *(const v8s*)&Vt[dcol][(c << 5) + (g << 3)];
            accp = __builtin_amdgcn_mfma_f32_16x16x32_bf16(a, b, accp, 0, 0, 0);
        }
        #pragma unroll
        for (int i = 0; i < 4; ++i) va[i] = vb[i];
    }
    #pragma unroll
    for (int r = 0; r < 4; ++r) {
        const int q = (g << 2) + r;
        Cb[(size_t)q * Dn + dcol] = accp[r] * invL[q];
    }

    {
        const int qq = tid >> 4, ii = tid & 15;
        const float inv = invL[qq];
        float* arow = Ab + (size_t)qq * Sn;
        #pragma unroll
        for (int c = 0; c < 16; ++c) {
            const int k0 = (c << 6) + (ii << 2);
            const ushort4 p = *(const ushort4*)&Ph[qq][k0];
            v4f o;
            o[0] = bf2f(p.x) * inv; o[1] = bf2f(p.y) * inv;
            o[2] = bf2f(p.z) * inv; o[3] = bf2f(p.w) * inv;
            *(v4f*)(arow + k0) = o;
        }
    }
}

extern "C" void kernel_launch(void* const* d_in, const int* in_sizes, int n_in,
                              void* d_out, int out_size, void* d_ws, size_t ws_size,
                              hipStream_t stream) {
    const float* Q    = (const float*)d_in[0];
    const float* K    = (const float*)d_in[1];
    const float* V    = (const float*)d_in[2];
    const int*   mask = (const int*)d_in[3];

    float* ctx  = (float*)d_out;                           // (B,H,S,D)
    float* attn = (float*)d_out + (size_t)128 * Sn * Dn;   // (B,H,S,S)

    const size_t NELEM = (size_t)128 * Sn * Dn;            // 8,388,608
    const size_t NEED  = NELEM * 6;                        // KF 33.5MB + VF 16.8MB

    if (ws_size >= NEED) {
        unsigned short* KF = (unsigned short*)d_ws;        // hi/lo frag-interleaved
        unsigned short* VF = KF + NELEM * 2;               // V^T frag-interleaved
        prep_kf<<<2048, 256, 0, stream>>>(K, KF);
        prep_vf<<<2048, 256, 0, stream>>>(V, VF);
        fused_attn_c2<<<128 * 64, 256, 0, stream>>>(KF, VF, Q, mask, attn, ctx);
    } else {
        fused_attn_fb<<<128 * 64, 256, 0, stream>>>(Q, K, V, mask, attn, ctx);
    }
}

// Round 13
// 314.425 us; speedup vs baseline: 1.1867x; 1.1337x over previous
//
#include <hip/hip_runtime.h>

#define Sn 1024
#define Dn 64
#define PH_LD 1032   // ushorts/row: 516 dw ≡ 4 (mod 32) -> conflict-min writes/reads (verified r10)
#define K_LD 72
#define V_LD 72

typedef short v8s __attribute__((ext_vector_type(8)));
typedef unsigned short v8u __attribute__((ext_vector_type(8)));
typedef float v4f __attribute__((ext_vector_type(4)));
typedef int   v4i __attribute__((ext_vector_type(4)));

#define LGKM0()  asm volatile("s_waitcnt lgkmcnt(0)" ::: "memory")
#define SBAR()   do { asm volatile("" ::: "memory"); __builtin_amdgcn_s_barrier(); \
                      __builtin_amdgcn_sched_barrier(0); } while (0)

__device__ __forceinline__ unsigned short f2bf(float x) {
    union { float f; unsigned u; } v; v.f = x;
    return (unsigned short)((v.u + 0x7FFFu + ((v.u >> 16) & 1u)) >> 16);
}
__device__ __forceinline__ float bf2f(unsigned short h) {
    union { float f; unsigned u; } v; v.u = ((unsigned)h) << 16;
    return v.f;
}
__device__ __forceinline__ void split2(float x, unsigned short& h, unsigned short& l) {
    unsigned short hs = f2bf(x);
    h = hs; l = f2bf(x - bf2f(hs));
}

// ---- prep: K -> fragment-interleaved bf16 hi/lo ----
// KF[bh][t64][sub][f][lane][8]; fused fragment load = 64 lanes x 16B contiguous.
__global__ __launch_bounds__(256) void prep_kf(const float* __restrict__ K,
    unsigned short* __restrict__ KF)
{
    const int bh = blockIdx.x >> 4, kt = blockIdx.x & 15;
    const int t = threadIdx.x;
    const int w = t >> 6, lane = t & 63;
    const int fr = lane & 15, g = lane >> 4;
    const float* src = K + (((size_t)(bh << 10) + (kt << 6) + (w << 4) + fr) << 6);
    const v4f a0 = __builtin_nontemporal_load((const v4f*)(src + (g << 3)));
    const v4f a1 = __builtin_nontemporal_load((const v4f*)(src + (g << 3) + 4));
    const v4f b0 = __builtin_nontemporal_load((const v4f*)(src + 32 + (g << 3)));
    const v4f b1 = __builtin_nontemporal_load((const v4f*)(src + 32 + (g << 3) + 4));
    v8u h0, h1, l0, l1;
    #pragma unroll
    for (int j = 0; j < 4; ++j) {
        unsigned short hh, ll;
        split2(a0[j], hh, ll); h0[j] = hh;     l0[j] = ll;
        split2(a1[j], hh, ll); h0[4 + j] = hh; l0[4 + j] = ll;
        split2(b0[j], hh, ll); h1[j] = hh;     l1[j] = ll;
        split2(b1[j], hh, ll); h1[4 + j] = hh; l1[4 + j] = ll;
    }
    unsigned short* dst = KF + ((size_t)bh << 17) + ((size_t)((kt << 2) + w) << 11) + (lane << 3);
    *(v8u*)(dst)        = h0;
    *(v8u*)(dst + 512)  = h1;
    *(v8u*)(dst + 1024) = l0;
    *(v8u*)(dst + 1536) = l1;
}

// ---- prep: V -> fragment-interleaved V^T bf16 ----
__global__ __launch_bounds__(256) void prep_vf(const float* __restrict__ V,
    unsigned short* __restrict__ VF)
{
    __shared__ float Ts[64][65];
    const int bh = blockIdx.x >> 4, kt = blockIdx.x & 15;
    const int t = threadIdx.x;
    {
        const int r = t >> 2, cs = (t & 3) << 4;
        const float* src = V + ((size_t)bh * Sn + (kt << 6) + r) * Dn + cs;
        const v4f a = __builtin_nontemporal_load((const v4f*)src);
        const v4f b = __builtin_nontemporal_load((const v4f*)src + 1);
        const v4f c = __builtin_nontemporal_load((const v4f*)src + 2);
        const v4f d = __builtin_nontemporal_load((const v4f*)src + 3);
        #pragma unroll
        for (int j = 0; j < 4; ++j) {
            Ts[r][cs + j]      = a[j];
            Ts[r][cs + 4 + j]  = b[j];
            Ts[r][cs + 8 + j]  = c[j];
            Ts[r][cs + 12 + j] = d[j];
        }
    }
    __syncthreads();
    {
        const int w = t >> 6, lane = t & 63;
        const int fr = lane & 15, g = lane >> 4;
        const int d = (w << 4) + fr;
        unsigned short* dst = VF + ((size_t)bh << 16) + ((size_t)((kt << 2) + w) << 10) + (lane << 3);
        v8u o0, o1;
        #pragma unroll
        for (int j = 0; j < 8; ++j) o0[j] = f2bf(Ts[(g << 3) + j][d]);
        #pragma unroll
        for (int j = 0; j < 8; ++j) o1[j] = f2bf(Ts[32 + (g << 3) + j][d]);
        *(v8u*)dst         = o0;
        *(v8u*)(dst + 512) = o1;
    }
}

// ---- prep: mask int32 -> bit-packed u64 words ----
__global__ __launch_bounds__(256) void prep_m(const int* __restrict__ M,
    unsigned long long* __restrict__ MW)
{
    const int NW = 2097152;
    const int lane = threadIdx.x & 63;
    const int wave = (blockIdx.x << 2) + (threadIdx.x >> 6);
    const int nwaves = gridDim.x << 2;
    for (int w0 = wave << 3; w0 < NW; w0 += nwaves << 3) {
        unsigned long long b[8];
        #pragma unroll
        for (int s = 0; s < 8; ++s) {
            const int v = __builtin_nontemporal_load(&M[((size_t)(w0 + s) << 6) + lane]);
            b[s] = __ballot(v != 0);
        }
        if (lane == 0) {
            ulonglong2* dst = (ulonglong2*)(MW + w0);
            ulonglong2 p0, p1, p2, p3;
            p0.x = b[0]; p0.y = b[1]; p1.x = b[2]; p1.y = b[3];
            p2.x = b[4]; p2.y = b[5]; p3.x = b[6]; p3.y = b[7];
            dst[0] = p0; dst[1] = p1; dst[2] = p2; dst[3] = p3;
        }
    }
}

// ---- fused attention: 32 q-rows/block, 8 waves, 2 blocks/CU ----
// Halves per-bh block count (64->32) => halves L2 re-read traffic (the r10
// limiter). Wave w covers k-slice w*16 of a 128-wide k-tile; computes BOTH
// q-halves (12 MFMA/iter). KF fragment index = kt*8 + w (layout unchanged).
__global__ __launch_bounds__(512, 4) void fused_attn_w(
    const unsigned short* __restrict__ KFG, const unsigned short* __restrict__ VFG,
    const float* __restrict__ Q, const unsigned long long* __restrict__ MW,
    float* __restrict__ attnO, float* __restrict__ ctxO)
{
    __shared__ unsigned short Ph[32][PH_LD];
    __shared__ float rsumW[8][32];
    __shared__ float invL[32];

    const int tid  = threadIdx.x;
    const int lane = tid & 63;
    const int w    = tid >> 6;     // 0..7
    const int fr   = lane & 15;
    const int g    = lane >> 4;

    // bijective XCD swizzle: 4096 blocks, each bh's 32 blocks on one XCD
    const int swz = ((blockIdx.x & 7) << 9) + (blockIdx.x >> 3);
    const int bh = swz >> 5;
    const int q0 = (swz & 31) << 5;

    const float* Qb = Q + (size_t)bh * Sn * Dn + (size_t)q0 * Dn;
    float*       Ab = attnO + (size_t)bh * Sn * Sn + (size_t)q0 * Sn;
    float*       Cb = ctxO  + (size_t)bh * Sn * Dn + (size_t)q0 * Dn;
    const unsigned short* KFb = KFG + ((size_t)bh << 17);
    const unsigned short* VFb = VFG + ((size_t)bh << 16);
    // mask-bit words: MW[bh][row][16]; word j covers k in [j*64,(j+1)*64)
    const unsigned long long* mwp0 = MW + ((size_t)bh << 14) + ((size_t)(q0 + fr) << 4);
    const unsigned long long* mwp1 = mwp0 + (16 << 4);   // row +16

    // Q B-fragments for both q-halves
    v8s qh0[2], qh1[2], ql0[2], ql1[2];
    #pragma unroll
    for (int h = 0; h < 2; ++h) {
        const float* qp = Qb + (size_t)((h << 4) + fr) * Dn + (g << 3);
        float x0[8], x1[8];
        *(v4f*)&x0[0] = *(const v4f*)qp;
        *(v4f*)&x0[4] = *(const v4f*)(qp + 4);
        *(v4f*)&x1[0] = *(const v4f*)(qp + 32);
        *(v4f*)&x1[4] = *(const v4f*)(qp + 36);
        #pragma unroll
        for (int i = 0; i < 8; ++i) {
            unsigned short hh, ll;
            split2(x0[i], hh, ll); qh0[h][i] = (short)hh; ql0[h][i] = (short)ll;
            split2(x1[i], hh, ll); qh1[h][i] = (short)hh; ql1[h][i] = (short)ll;
        }
    }

    const int jbase = w >> 2;            // mask word parity
    const int sh    = ((w & 3) << 4) + (g << 2);   // bit shift in word

#define LDK(kt, h0_, h1_, l0_, l1_) do {                                           \
        const unsigned short* _p = KFb + ((size_t)(((kt) << 3) + w) << 11) + (lane << 3); \
        h0_ = *(const v8s*)_p;          h1_ = *(const v8s*)(_p + 512);             \
        l0_ = *(const v8s*)(_p + 1024); l1_ = *(const v8s*)(_p + 1536);            \
    } while (0)

#define STEPA(kh0, kh1, kl0, kl1, mv0, mv1, kt) do {                               \
        v4f acc0 = {0.f, 0.f, 0.f, 0.f};                                           \
        v4f acc1 = {0.f, 0.f, 0.f, 0.f};                                           \
        __builtin_amdgcn_s_setprio(1);                                             \
        acc0 = __builtin_amdgcn_mfma_f32_16x16x32_bf16(kh0, qh0[0], acc0, 0, 0, 0);\
        acc1 = __builtin_amdgcn_mfma_f32_16x16x32_bf16(kh0, qh0[1], acc1, 0, 0, 0);\
        acc0 = __builtin_amdgcn_mfma_f32_16x16x32_bf16(kh1, qh1[0], acc0, 0, 0, 0);\
        acc1 = __builtin_amdgcn_mfma_f32_16x16x32_bf16(kh1, qh1[1], acc1, 0, 0, 0);\
        acc0 = __builtin_amdgcn_mfma_f32_16x16x32_bf16(kl0, qh0[0], acc0, 0, 0, 0);\
        acc1 = __builtin_amdgcn_mfma_f32_16x16x32_bf16(kl0, qh0[1], acc1, 0, 0, 0);\
        acc0 = __builtin_amdgcn_mfma_f32_16x16x32_bf16(kl1, qh1[0], acc0, 0, 0, 0);\
        acc1 = __builtin_amdgcn_mfma_f32_16x16x32_bf16(kl1, qh1[1], acc1, 0, 0, 0);\
        acc0 = __builtin_amdgcn_mfma_f32_16x16x32_bf16(kh0, ql0[0], acc0, 0, 0, 0);\
        acc1 = __builtin_amdgcn_mfma_f32_16x16x32_bf16(kh0, ql0[1], acc1, 0, 0, 0);\
        acc0 = __builtin_amdgcn_mfma_f32_16x16x32_bf16(kh1, ql1[0], acc0, 0, 0, 0);\
        acc1 = __builtin_amdgcn_mfma_f32_16x16x32_bf16(kh1, ql1[1], acc1, 0, 0, 0);\
        __builtin_amdgcn_s_setprio(0);                                             \
        const int kcol = ((kt) << 7) + ((w & 3) << 4) + ((w >> 2) << 6) + (g << 2);\
        const unsigned mb0 = (unsigned)((mv0) >> sh);                              \
        const unsigned mb1 = (unsigned)((mv1) >> sh);                              \
        const float e00 = (mb0 & 1u) ? 1.0f : __expf(acc0[0]);                     \
        const float e01 = (mb0 & 2u) ? 1.0f : __expf(acc0[1]);                     \
        const float e02 = (mb0 & 4u) ? 1.0f : __expf(acc0[2]);                     \
        const float e03 = (mb0 & 8u) ? 1.0f : __expf(acc0[3]);                     \
        const float e10 = (mb1 & 1u) ? 1.0f : __expf(acc1[0]);                     \
        const float e11 = (mb1 & 2u) ? 1.0f : __expf(acc1[1]);                     \
        const float e12 = (mb1 & 4u) ? 1.0f : __expf(acc1[2]);                     \
        const float e13 = (mb1 & 8u) ? 1.0f : __expf(acc1[3]);                     \
        rs0 += (e00 + e01) + (e02 + e03);                                          \
        rs1 += (e10 + e11) + (e12 + e13);                                          \
        ushort4 pk0, pk1;                                                          \
        pk0.x = f2bf(e00); pk0.y = f2bf(e01); pk0.z = f2bf(e02); pk0.w = f2bf(e03);\
        pk1.x = f2bf(e10); pk1.y = f2bf(e11); pk1.z = f2bf(e12); pk1.w = f2bf(e13);\
        *(ushort4*)&Ph[fr][kcol]      = pk0;                                       \
        *(ushort4*)&Ph[16 + fr][kcol] = pk1;                                       \
    } while (0)

    float rs0 = 0.f, rs1 = 0.f;

    // ---- Phase A: 8 iters of 128-k tiles; barrier-free; depth-2 prefetch ----
    {
        v8s h0[2], h1[2], l0[2], l1[2];
        unsigned long long m0[2], m1[2];
        LDK(0, h0[0], h1[0], l0[0], l1[0]);
        LDK(1, h0[1], h1[1], l0[1], l1[1]);
        m0[0] = mwp0[jbase];     m1[0] = mwp1[jbase];
        m0[1] = mwp0[jbase + 2]; m1[1] = mwp1[jbase + 2];
        #pragma unroll
        for (int kt = 0; kt < 8; ++kt) {
            STEPA(h0[kt & 1], h1[kt & 1], l0[kt & 1], l1[kt & 1], m0[kt & 1], m1[kt & 1], kt);
            if (kt + 2 < 8) {
                LDK(kt + 2, h0[kt & 1], h1[kt & 1], l0[kt & 1], l1[kt & 1]);
                m0[kt & 1] = mwp0[jbase + ((kt + 2) << 1)];
                m1[kt & 1] = mwp1[jbase + ((kt + 2) << 1)];
            }
        }
    }

    // NOTE: kcol above interleaves (w>>2)<<6; coverage check: w 0..7, kt 0..7 ->
    // kcol base = kt*128 + (w>>2)*64 + (w&3)*16 spans all 64 16-blocks. Mask word
    // j = jbase + kt*2 matches k block [j*64,(j+1)*64) = kt*128 + (w>>2)*64. OK.

    // ---- row-sum reduce (only barriers; raw, no vmcnt drain) ----
    rs0 += __shfl_xor(rs0, 16);
    rs0 += __shfl_xor(rs0, 32);
    rs1 += __shfl_xor(rs1, 16);
    rs1 += __shfl_xor(rs1, 32);
    if (g == 0) { rsumW[w][fr] = rs0; rsumW[w][16 + fr] = rs1; }
    __builtin_amdgcn_sched_barrier(0);
    LGKM0();
    SBAR();
    if (tid < 32) {
        float s = 0.f;
        #pragma unroll
        for (int ww = 0; ww < 8; ++ww) s += rsumW[ww][tid];
        invL[tid] = 1.0f / s;
    }
    __builtin_amdgcn_sched_barrier(0);
    LGKM0();
    SBAR();

#define LDV(kt, v0, v1) do {                                                       \
        const unsigned short* _p = VFb + ((size_t)(((kt) << 2) + (w & 3)) << 10) + (lane << 3); \
        v0 = *(const v8s*)_p;  v1 = *(const v8s*)(_p + 512);                       \
    } while (0)

    const int qbase = (w >> 2) << 4;     // q-half this wave produces in Phase B

#define STEPB(v0, v1, kt) do {                                                     \
        const v8s a0 = *(const v8s*)&Ph[qbase + fr][((kt) << 6) + (g << 3)];       \
        const v8s a1 = *(const v8s*)&Ph[qbase + fr][((kt) << 6) + 32 + (g << 3)];  \
        __builtin_amdgcn_s_setprio(1);                                             \
        accp = __builtin_amdgcn_mfma_f32_16x16x32_bf16(a0, v0, accp, 0, 0, 0);     \
        accp = __builtin_amdgcn_mfma_f32_16x16x32_bf16(a1, v1, accp, 0, 0, 0);     \
        __builtin_amdgcn_s_setprio(0);                                             \
    } while (0)

    // Issue first V frag loads BEFORE the attn store burst (in-order vmcnt).
    v8s va0, va1, vb0, vb1;
    LDV(0, va0, va1);
    LDV(1, vb0, vb1);

    // ---- write normalized attn (NT burst drains under Phase B) ----
    {
        const int qq = tid >> 4, ii = tid & 15;
        const float inv = invL[qq];
        float* arow = Ab + (size_t)qq * Sn;
        #pragma unroll
        for (int c = 0; c < 16; ++c) {
            const int k0 = (c << 6) + (ii << 2);
            const ushort4 p = *(const ushort4*)&Ph[qq][k0];
            v4f o;
            o[0] = bf2f(p.x) * inv; o[1] = bf2f(p.y) * inv;
            o[2] = bf2f(p.z) * inv; o[3] = bf2f(p.w) * inv;
            __builtin_nontemporal_store(o, (v4f*)(arow + k0));
        }
    }

    // ---- Phase B: barrier-free, coalesced V frags ----
    const int dcol = ((w & 3) << 4) + fr;
    v4f accp = {0.f, 0.f, 0.f, 0.f};
    for (int kt = 0; kt < 16; kt += 2) {
        const int k2 = (kt + 2 < 16) ? kt + 2 : kt;
        const int k3 = (kt + 3 < 16) ? kt + 3 : kt;
        v8s vc0, vc1, vd0, vd1;
        LDV(k2, vc0, vc1);
        LDV(k3, vd0, vd1);
        STEPB(va0, va1, kt);
        STEPB(vb0, vb1, kt + 1);
        va0 = vc0; va1 = vc1;
        vb0 = vd0; vb1 = vd1;
    }
    #pragma unroll
    for (int r = 0; r < 4; ++r) {
        const int q = qbase + (g << 2) + r;
        __builtin_nontemporal_store(accp[r] * invL[q], &Cb[(size_t)q * Dn + dcol]);
    }
#undef LDK
#undef STEPA
#undef LDV
#undef STEPB
}

// ---------------- fallback (round-3 kernel, in-kernel split) ----------------
__global__ __launch_bounds__(256, 3) void fused_attn_fb(
    const float* __restrict__ Q, const float* __restrict__ K,
    const float* __restrict__ V, const int* __restrict__ M,
    float* __restrict__ attnO, float* __restrict__ ctxO)
{
    __shared__ unsigned short Ph[16][1048];
    __shared__ __align__(16) unsigned short Kraw[2 * 64 * K_LD];
    __shared__ float rsumW[4][16];
    __shared__ float invL[16];

    unsigned short (*Khi)[K_LD] = (unsigned short (*)[K_LD])Kraw;
    unsigned short (*Klo)[K_LD] = (unsigned short (*)[K_LD])(Kraw + 64 * K_LD);
    unsigned short (*Vt)[V_LD]  = (unsigned short (*)[V_LD])Kraw;

    const int tid  = threadIdx.x;
    const int lane = tid & 63;
    const int w    = tid >> 6;
    const int fr   = lane & 15;
    const int g    = lane >> 4;

    const int bh = blockIdx.x >> 6;
    const int q0 = (blockIdx.x & 63) << 4;

    const float* Qb = Q + (size_t)bh * Sn * Dn + (size_t)q0 * Dn;
    const float* Kb = K + (size_t)bh * Sn * Dn;
    const float* Vb = V + (size_t)bh * Sn * Dn;
    const int*   Mb = M + (size_t)bh * Sn * Sn + (size_t)q0 * Sn;
    float*       Ab = attnO + (size_t)bh * Sn * Sn + (size_t)q0 * Sn;
    float*       Cb = ctxO  + (size_t)bh * Sn * Dn + (size_t)q0 * Dn;

    v8s qh0, qh1, ql0, ql1;
    {
        const float* qp = Qb + fr * Dn + (g << 3);
        float x0[8], x1[8];
        *(v4f*)&x0[0] = *(const v4f*)qp;
        *(v4f*)&x0[4] = *(const v4f*)(qp + 4);
        *(v4f*)&x1[0] = *(const v4f*)(qp + 32);
        *(v4f*)&x1[4] = *(const v4f*)(qp + 36);
        #pragma unroll
        for (int i = 0; i < 8; ++i) {
            unsigned short hh, ll;
            split2(x0[i], hh, ll); qh0[i] = (short)hh; ql0[i] = (short)ll;
            split2(x1[i], hh, ll); qh1[i] = (short)hh; ql1[i] = (short)ll;
        }
    }

    const int srow = tid >> 4;
    const int sc4  = (tid & 15) << 2;

    const int* mp = Mb + (size_t)fr * Sn + (w << 4) + (g << 2);
    v4i mv = *(const v4i*)mp;

    v4f ka[4];
    #pragma unroll
    for (int i = 0; i < 4; ++i)
        ka[i] = *(const v4f*)(Kb + (size_t)(srow + (i << 4)) * Dn + sc4);

    float rs = 0.f;

    for (int kt = 0; kt < 16; ++kt) {
        __syncthreads();
        v4f kb[4];
        if (kt < 15) {
            const float* kn = Kb + (size_t)((kt + 1) << 6) * Dn;
            #pragma unroll
            for (int i = 0; i < 4; ++i)
                kb[i] = *(const v4f*)(kn + (size_t)(srow + (i << 4)) * Dn + sc4);
        }
        v4i mnext = mv;
        if (kt < 15) mnext = *(const v4i*)(mp + ((kt + 1) << 6));

        #pragma unroll
        for (int i = 0; i < 4; ++i) {
            const int row = srow + (i << 4);
            ushort4 hv, lv;
            split2(ka[i][0], hv.x, lv.x); split2(ka[i][1], hv.y, lv.y);
            split2(ka[i][2], hv.z, lv.z); split2(ka[i][3], hv.w, lv.w);
            *(ushort4*)&Khi[row][sc4] = hv;
            *(ushort4*)&Klo[row][sc4] = lv;
        }
        __syncthreads();

        const int krow = (w << 4) + fr;
        const v8s kh0 = *(const v8s*)&Khi[krow][(g << 3)];
        const v8s kh1 = *(const v8s*)&Khi[krow][32 + (g << 3)];
        const v8s kl0 = *(const v8s*)&Klo[krow][(g << 3)];
        const v8s kl1 = *(const v8s*)&Klo[krow][32 + (g << 3)];

        v4f acc = {0.f, 0.f, 0.f, 0.f};
        acc = __builtin_amdgcn_mfma_f32_16x16x32_bf16(kh0, qh0, acc, 0, 0, 0);
        acc = __builtin_amdgcn_mfma_f32_16x16x32_bf16(kh1, qh1, acc, 0, 0, 0);
        acc = __builtin_amdgcn_mfma_f32_16x16x32_bf16(kl0, qh0, acc, 0, 0, 0);
        acc = __builtin_amdgcn_mfma_f32_16x16x32_bf16(kl1, qh1, acc, 0, 0, 0);
        acc = __builtin_amdgcn_mfma_f32_16x16x32_bf16(kh0, ql0, acc, 0, 0, 0);
        acc = __builtin_amdgcn_mfma_f32_16x16x32_bf16(kh1, ql1, acc, 0, 0, 0);

        const float e0 = mv[0] ? 1.0f : __expf(acc[0]);
        const float e1 = mv[1] ? 1.0f : __expf(acc[1]);
        const float e2 = mv[2] ? 1.0f : __expf(acc[2]);
        const float e3 = mv[3] ? 1.0f : __expf(acc[3]);
        rs += (e0 + e1) + (e2 + e3);
        ushort4 pk;
        pk.x = f2bf(e0); pk.y = f2bf(e1); pk.z = f2bf(e2); pk.w = f2bf(e3);
        *(ushort4*)&Ph[fr][(kt << 6) + (w << 4) + (g << 2)] = pk;

        mv = mnext;
        #pragma unroll
        for (int i = 0; i < 4; ++i) ka[i] = kb[i];
    }

    rs += __shfl_xor(rs, 16);
    rs += __shfl_xor(rs, 32);
    if (g == 0) rsumW[w][fr] = rs;
    __syncthreads();
    if (tid < 16) {
        const float s = rsumW[0][tid] + rsumW[1][tid] + rsumW[2][tid] + rsumW[3][tid];
        invL[tid] = 1.0f / s;
    }
    __syncthreads();

    const int dcol = (w << 4) + fr;
    v4f va[4];
    #pragma unroll
    for (int i = 0; i < 4; ++i)
        va[i] = *(const v4f*)(Vb + (size_t)(srow + (i << 4)) * Dn + sc4);

    v4f accp = {0.f, 0.f, 0.f, 0.f};
    for (int kt = 0; kt < 16; ++kt) {
        __syncthreads();
        v4f vb[4];
        if (kt < 15) {
            const float* vn = Vb + (size_t)((kt + 1) << 6) * Dn;
            #pragma unroll
            for (int i = 0; i < 4; ++i)
                vb[i] = *(const v4f*)(vn + (size_t)(srow + (i << 4)) * Dn + sc4);
        }
        #pragma unroll
        for (int i = 0; i < 4; ++i) {
            const int row = srow + (i << 4);
            Vt[sc4 + 0][row] = f2bf(va[i][0]);
            Vt[sc4 + 1][row] = f2bf(va[i][1]);
            Vt[sc4 + 2][row] = f2bf(va[i][2]);
            Vt[sc4 + 3][row] = f2bf(va[i][3]);
        }
        __syncthreads();

        #pragma unroll
        for (int c = 0; c < 2; ++c) {
            const int kc = (kt << 6) + (c << 5);
            const v8s a = *(const v8s*)&Ph[fr][kc + (g << 3)];
            const v8s b = *(const v8s*)&Vt[dcol][(c << 5) + (g << 3)];
            accp = __builtin_amdgcn_mfma_f32_16x16x32_bf16(a, b, accp, 0, 0, 0);
        }
        #pragma unroll
        for (int i = 0; i < 4; ++i) va[i] = vb[i];
    }
    #pragma unroll
    for (int r = 0; r < 4; ++r) {
        const int q = (g << 2) + r;
        Cb[(size_t)q * Dn + dcol] = accp[r] * invL[q];
    }

    {
        const int qq = tid >> 4, ii = tid & 15;
        const float inv = invL[qq];
        float* arow = Ab + (size_t)qq * Sn;
        #pragma unroll
        for (int c = 0; c < 16; ++c) {
            const int k0 = (c << 6) + (ii << 2);
            const ushort4 p = *(const ushort4*)&Ph[qq][k0];
            v4f o;
            o[0] = bf2f(p.x) * inv; o[1] = bf2f(p.y) * inv;
            o[2] = bf2f(p.z) * inv; o[3] = bf2f(p.w) * inv;
            *(v4f*)(arow + k0) = o;
        }
    }
}

extern "C" void kernel_launch(void* const* d_in, const int* in_sizes, int n_in,
                              void* d_out, int out_size, void* d_ws, size_t ws_size,
                              hipStream_t stream) {
    const float* Q    = (const float*)d_in[0];
    const float* K    = (const float*)d_in[1];
    const float* V    = (const float*)d_in[2];
    const int*   mask = (const int*)d_in[3];

    float* ctx  = (float*)d_out;                           // (B,H,S,D)
    float* attn = (float*)d_out + (size_t)128 * Sn * Dn;   // (B,H,S,S)

    const size_t NELEM = (size_t)128 * Sn * Dn;            // 8,388,608
    const size_t MWORDS = (size_t)128 * Sn * 16;           // 2,097,152 u64
    const size_t NEED  = NELEM * 6 + MWORDS * 8;           // KF+VF 50.3MB + bits 16.8MB

    if (ws_size >= NEED) {
        unsigned short* KF = (unsigned short*)d_ws;        // hi/lo frag-interleaved
        unsigned short* VF = KF + NELEM * 2;               // V^T frag-interleaved
        unsigned long long* MWp = (unsigned long long*)((char*)d_ws + NELEM * 6);
        prep_kf<<<2048, 256, 0, stream>>>(K, KF);
        prep_vf<<<2048, 256, 0, stream>>>(V, VF);
        prep_m<<<2048, 256, 0, stream>>>(mask, MWp);
        fused_attn_w<<<128 * 32, 512, 0, stream>>>(KF, VF, Q, MWp, attn, ctx);
    } else {
        fused_attn_fb<<<128 * 64, 256, 0, stream>>>(Q, K, V, mask, attn, ctx);
    }
}

// Round 14
// 301.233 us; speedup vs baseline: 1.2386x; 1.0438x over previous
//
#include <hip/hip_runtime.h>

#define Sn 1024
#define Dn 64
#define PH_LD 1032   // ushorts/row: 516 dw ≡ 4 (mod 32) -> conflict-min (verified r10)
#define K_LD 72
#define V_LD 72

typedef short v8s __attribute__((ext_vector_type(8)));
typedef unsigned short v8u __attribute__((ext_vector_type(8)));
typedef float v4f __attribute__((ext_vector_type(4)));
typedef int   v4i __attribute__((ext_vector_type(4)));

#define LGKM0()  asm volatile("s_waitcnt lgkmcnt(0)" ::: "memory")
#define SBAR()   do { asm volatile("" ::: "memory"); __builtin_amdgcn_s_barrier(); \
                      __builtin_amdgcn_sched_barrier(0); } while (0)

__device__ __forceinline__ unsigned short f2bf(float x) {
    union { float f; unsigned u; } v; v.f = x;
    return (unsigned short)((v.u + 0x7FFFu + ((v.u >> 16) & 1u)) >> 16);
}
__device__ __forceinline__ float bf2f(unsigned short h) {
    union { float f; unsigned u; } v; v.u = ((unsigned)h) << 16;
    return v.f;
}
__device__ __forceinline__ void split2(float x, unsigned short& h, unsigned short& l) {
    unsigned short hs = f2bf(x);
    h = hs; l = f2bf(x - bf2f(hs));
}

// ---- ONE prep kernel, task-split by blockIdx: KF | VF | mask bits ----
// KF/VF conversion (~170MB) hides inside the 537MB mask stream's BW shadow.
__global__ __launch_bounds__(256) void prep_all(
    const float* __restrict__ K, const float* __restrict__ V,
    const int* __restrict__ M,
    unsigned short* __restrict__ KF, unsigned short* __restrict__ VF,
    unsigned long long* __restrict__ MW)
{
    __shared__ float Ts[64][65];
    const int bid = blockIdx.x;
    const int t = threadIdx.x;

    if (bid < 2048) {
        // ---- K -> fragment-interleaved bf16 hi/lo ----
        const int bh = bid >> 4, kt = bid & 15;
        const int w = t >> 6, lane = t & 63;
        const int fr = lane & 15, g = lane >> 4;
        const float* src = K + (((size_t)(bh << 10) + (kt << 6) + (w << 4) + fr) << 6);
        const v4f a0 = __builtin_nontemporal_load((const v4f*)(src + (g << 3)));
        const v4f a1 = __builtin_nontemporal_load((const v4f*)(src + (g << 3) + 4));
        const v4f b0 = __builtin_nontemporal_load((const v4f*)(src + 32 + (g << 3)));
        const v4f b1 = __builtin_nontemporal_load((const v4f*)(src + 32 + (g << 3) + 4));
        v8u h0, h1, l0, l1;
        #pragma unroll
        for (int j = 0; j < 4; ++j) {
            unsigned short hh, ll;
            split2(a0[j], hh, ll); h0[j] = hh;     l0[j] = ll;
            split2(a1[j], hh, ll); h0[4 + j] = hh; l0[4 + j] = ll;
            split2(b0[j], hh, ll); h1[j] = hh;     l1[j] = ll;
            split2(b1[j], hh, ll); h1[4 + j] = hh; l1[4 + j] = ll;
        }
        unsigned short* dst = KF + ((size_t)bh << 17) + ((size_t)((kt << 2) + w) << 11) + (lane << 3);
        *(v8u*)(dst)        = h0;
        *(v8u*)(dst + 512)  = h1;
        *(v8u*)(dst + 1024) = l0;
        *(v8u*)(dst + 1536) = l1;
    } else if (bid < 4096) {
        // ---- V -> fragment-interleaved V^T bf16 ----
        const int b2 = bid - 2048;
        const int bh = b2 >> 4, kt = b2 & 15;
        {
            const int r = t >> 2, cs = (t & 3) << 4;
            const float* src = V + ((size_t)bh * Sn + (kt << 6) + r) * Dn + cs;
            const v4f a = __builtin_nontemporal_load((const v4f*)src);
            const v4f b = __builtin_nontemporal_load((const v4f*)src + 1);
            const v4f c = __builtin_nontemporal_load((const v4f*)src + 2);
            const v4f d = __builtin_nontemporal_load((const v4f*)src + 3);
            #pragma unroll
            for (int j = 0; j < 4; ++j) {
                Ts[r][cs + j]      = a[j];
                Ts[r][cs + 4 + j]  = b[j];
                Ts[r][cs + 8 + j]  = c[j];
                Ts[r][cs + 12 + j] = d[j];
            }
        }
        __syncthreads();
        {
            const int w = t >> 6, lane = t & 63;
            const int fr = lane & 15, g = lane >> 4;
            const int d = (w << 4) + fr;
            unsigned short* dst = VF + ((size_t)bh << 16) + ((size_t)((kt << 2) + w) << 10) + (lane << 3);
            v8u o0, o1;
            #pragma unroll
            for (int j = 0; j < 8; ++j) o0[j] = f2bf(Ts[(g << 3) + j][d]);
            #pragma unroll
            for (int j = 0; j < 8; ++j) o1[j] = f2bf(Ts[32 + (g << 3) + j][d]);
            *(v8u*)dst         = o0;
            *(v8u*)(dst + 512) = o1;
        }
    } else {
        // ---- mask int32 -> bit-packed u64 words (grid-stride) ----
        const int NW = 2097152;   // 128*1024*1024 / 64
        const int lane = t & 63;
        const int wave = ((bid - 4096) << 2) + (t >> 6);
        const int nwaves = 2048 << 2;
        for (int w0 = wave << 3; w0 < NW; w0 += nwaves << 3) {
            unsigned long long b[8];
            #pragma unroll
            for (int s = 0; s < 8; ++s) {
                const int v = __builtin_nontemporal_load(&M[((size_t)(w0 + s) << 6) + lane]);
                b[s] = __ballot(v != 0);
            }
            if (lane == 0) {
                ulonglong2* dst = (ulonglong2*)(MW + w0);
                ulonglong2 p0, p1, p2, p3;
                p0.x = b[0]; p0.y = b[1]; p1.x = b[2]; p1.y = b[3];
                p2.x = b[4]; p2.y = b[5]; p3.x = b[6]; p3.y = b[7];
                dst[0] = p0; dst[1] = p1; dst[2] = p2; dst[3] = p3;
            }
        }
    }
}

// ---- fused attention: r10 structure + depth-4 prefetch both phases ----
// Block: 16 q-rows, 4 waves, 4 blocks/CU (LDS = Ph only, 33 KB). Barrier-free
// phases; every fragment load = one coalesced 1KB dwordx4 from XCD-local L2;
// depth-4 static ping-pong (~400+ cyc issue lead) covers L2 latency.
__global__ __launch_bounds__(256, 4) void fused_attn_c(
    const unsigned short* __restrict__ KFG, const unsigned short* __restrict__ VFG,
    const float* __restrict__ Q, const unsigned long long* __restrict__ MW,
    float* __restrict__ attnO, float* __restrict__ ctxO)
{
    __shared__ unsigned short Ph[16][PH_LD];
    __shared__ float rsumW[4][16];
    __shared__ float invL[16];

    const int tid  = threadIdx.x;
    const int lane = tid & 63;
    const int w    = tid >> 6;
    const int fr   = lane & 15;
    const int g    = lane >> 4;

    // bijective XCD swizzle: all 64 q-blocks of one bh on one XCD
    const int swz = ((blockIdx.x & 7) << 10) + (blockIdx.x >> 3);
    const int bh = swz >> 6;
    const int q0 = (swz & 63) << 4;

    const float* Qb = Q + (size_t)bh * Sn * Dn + (size_t)q0 * Dn;
    float*       Ab = attnO + (size_t)bh * Sn * Sn + (size_t)q0 * Sn;
    float*       Cb = ctxO  + (size_t)bh * Sn * Dn + (size_t)q0 * Dn;
    const unsigned short* KFb = KFG + ((size_t)bh << 17);
    const unsigned short* VFb = VFG + ((size_t)bh << 16);
    const unsigned long long* mwp = MW + ((size_t)bh << 14) + ((size_t)(q0 + fr) << 4);

    // Q B-fragments (once per block)
    v8s qh0, qh1, ql0, ql1;
    {
        const float* qp = Qb + fr * Dn + (g << 3);
        float x0[8], x1[8];
        *(v4f*)&x0[0] = *(const v4f*)qp;
        *(v4f*)&x0[4] = *(const v4f*)(qp + 4);
        *(v4f*)&x1[0] = *(const v4f*)(qp + 32);
        *(v4f*)&x1[4] = *(const v4f*)(qp + 36);
        #pragma unroll
        for (int i = 0; i < 8; ++i) {
            unsigned short hh, ll;
            split2(x0[i], hh, ll); qh0[i] = (short)hh; ql0[i] = (short)ll;
            split2(x1[i], hh, ll); qh1[i] = (short)hh; ql1[i] = (short)ll;
        }
    }

    const int sh = (w << 4) + (g << 2);

#define LDK(kt, h0_, h1_, l0_, l1_) do {                                           \
        const unsigned short* _p = KFb + ((size_t)(((kt) << 2) + w) << 11) + (lane << 3); \
        h0_ = *(const v8s*)_p;          h1_ = *(const v8s*)(_p + 512);             \
        l0_ = *(const v8s*)(_p + 1024); l1_ = *(const v8s*)(_p + 1536);            \
    } while (0)

#define STEPA(h0_, h1_, l0_, l1_, mwv, kt) do {                                    \
        v4f acc = {0.f, 0.f, 0.f, 0.f};                                            \
        __builtin_amdgcn_s_setprio(1);                                             \
        acc = __builtin_amdgcn_mfma_f32_16x16x32_bf16(h0_, qh0, acc, 0, 0, 0);     \
        acc = __builtin_amdgcn_mfma_f32_16x16x32_bf16(h1_, qh1, acc, 0, 0, 0);     \
        acc = __builtin_amdgcn_mfma_f32_16x16x32_bf16(l0_, qh0, acc, 0, 0, 0);     \
        acc = __builtin_amdgcn_mfma_f32_16x16x32_bf16(l1_, qh1, acc, 0, 0, 0);     \
        acc = __builtin_amdgcn_mfma_f32_16x16x32_bf16(h0_, ql0, acc, 0, 0, 0);     \
        acc = __builtin_amdgcn_mfma_f32_16x16x32_bf16(h1_, ql1, acc, 0, 0, 0);     \
        __builtin_amdgcn_s_setprio(0);                                             \
        const unsigned mb = (unsigned)((mwv) >> sh);                               \
        const float e0 = (mb & 1u) ? 1.0f : __expf(acc[0]);                        \
        const float e1 = (mb & 2u) ? 1.0f : __expf(acc[1]);                        \
        const float e2 = (mb & 4u) ? 1.0f : __expf(acc[2]);                        \
        const float e3 = (mb & 8u) ? 1.0f : __expf(acc[3]);                        \
        rs += (e0 + e1) + (e2 + e3);                                               \
        ushort4 pk;                                                                \
        pk.x = f2bf(e0); pk.y = f2bf(e1); pk.z = f2bf(e2); pk.w = f2bf(e3);        \
        *(ushort4*)&Ph[fr][((kt) << 6) + (w << 4) + (g << 2)] = pk;                \
    } while (0)

    float rs = 0.f;

    // ---- Phase A: barrier-free; depth-4 K slots + depth-4 mask ring ----
    {
        v8s h0[4], h1[4], l0[4], l1[4];
        unsigned long long mk[4];
        LDK(0, h0[0], h1[0], l0[0], l1[0]);
        LDK(1, h0[1], h1[1], l0[1], l1[1]);
        LDK(2, h0[2], h1[2], l0[2], l1[2]);
        LDK(3, h0[3], h1[3], l0[3], l1[3]);
        mk[0] = mwp[0]; mk[1] = mwp[1]; mk[2] = mwp[2]; mk[3] = mwp[3];
        #pragma unroll
        for (int kt = 0; kt < 16; ++kt) {
            STEPA(h0[kt & 3], h1[kt & 3], l0[kt & 3], l1[kt & 3], mk[kt & 3], kt);
            if (kt + 4 < 16) {
                LDK(kt + 4, h0[kt & 3], h1[kt & 3], l0[kt & 3], l1[kt & 3]);
                mk[kt & 3] = mwp[kt + 4];
            }
        }
    }

    // ---- row-sum reduce (only barriers; raw, no vmcnt drain) ----
    rs += __shfl_xor(rs, 16);
    rs += __shfl_xor(rs, 32);
    if (g == 0) rsumW[w][fr] = rs;
    __builtin_amdgcn_sched_barrier(0);
    LGKM0();
    SBAR();
    if (tid < 16) {
        const float s = rsumW[0][tid] + rsumW[1][tid] + rsumW[2][tid] + rsumW[3][tid];
        invL[tid] = 1.0f / s;
    }
    __builtin_amdgcn_sched_barrier(0);
    LGKM0();
    SBAR();

#define LDV(kt, v0_, v1_) do {                                                     \
        const unsigned short* _p = VFb + ((size_t)(((kt) << 2) + w) << 10) + (lane << 3); \
        v0_ = *(const v8s*)_p;  v1_ = *(const v8s*)(_p + 512);                     \
    } while (0)

#define STEPB(v0_, v1_, kt) do {                                                   \
        const v8s a0 = *(const v8s*)&Ph[fr][((kt) << 6) + (g << 3)];               \
        const v8s a1 = *(const v8s*)&Ph[fr][((kt) << 6) + 32 + (g << 3)];          \
        __builtin_amdgcn_s_setprio(1);                                             \
        accp = __builtin_amdgcn_mfma_f32_16x16x32_bf16(a0, v0_, accp, 0, 0, 0);    \
        accp = __builtin_amdgcn_mfma_f32_16x16x32_bf16(a1, v1_, accp, 0, 0, 0);    \
        __builtin_amdgcn_s_setprio(0);                                             \
    } while (0)

    // Issue first V frag loads BEFORE the attn store burst (in-order vmcnt:
    // loads before stores -> Phase B never waits on the store stream).
    v8s v0s[4], v1s[4];
    LDV(0, v0s[0], v1s[0]);
    LDV(1, v0s[1], v1s[1]);
    LDV(2, v0s[2], v1s[2]);
    LDV(3, v0s[3], v1s[3]);

    // ---- write normalized attn (NT burst drains under Phase B) ----
    {
        const int qq = tid >> 4, ii = tid & 15;
        const float inv = invL[qq];
        float* arow = Ab + (size_t)qq * Sn;
        #pragma unroll
        for (int c = 0; c < 16; ++c) {
            const int k0 = (c << 6) + (ii << 2);
            const ushort4 p = *(const ushort4*)&Ph[qq][k0];
            v4f o;
            o[0] = bf2f(p.x) * inv; o[1] = bf2f(p.y) * inv;
            o[2] = bf2f(p.z) * inv; o[3] = bf2f(p.w) * inv;
            __builtin_nontemporal_store(o, (v4f*)(arow + k0));
        }
    }

    // ---- Phase B: barrier-free, depth-4 V slots ----
    const int dcol = (w << 4) + fr;
    v4f accp = {0.f, 0.f, 0.f, 0.f};
    #pragma unroll
    for (int kt = 0; kt < 16; ++kt) {
        STEPB(v0s[kt & 3], v1s[kt & 3], kt);
        if (kt + 4 < 16) LDV(kt + 4, v0s[kt & 3], v1s[kt & 3]);
    }
    #pragma unroll
    for (int r = 0; r < 4; ++r) {
        const int q = (g << 2) + r;
        __builtin_nontemporal_store(accp[r] * invL[q], &Cb[(size_t)q * Dn + dcol]);
    }
#undef LDK
#undef STEPA
#undef LDV
#undef STEPB
}

// ---------------- fallback (round-3 kernel, in-kernel split) ----------------
__global__ __launch_bounds__(256, 3) void fused_attn_fb(
    const float* __restrict__ Q, const float* __restrict__ K,
    const float* __restrict__ V, const int* __restrict__ M,
    float* __restrict__ attnO, float* __restrict__ ctxO)
{
    __shared__ unsigned short Ph[16][1048];
    __shared__ __align__(16) unsigned short Kraw[2 * 64 * K_LD];
    __shared__ float rsumW[4][16];
    __shared__ float invL[16];

    unsigned short (*Khi)[K_LD] = (unsigned short (*)[K_LD])Kraw;
    unsigned short (*Klo)[K_LD] = (unsigned short (*)[K_LD])(Kraw + 64 * K_LD);
    unsigned short (*Vt)[V_LD]  = (unsigned short (*)[V_LD])Kraw;

    const int tid  = threadIdx.x;
    const int lane = tid & 63;
    const int w    = tid >> 6;
    const int fr   = lane & 15;
    const int g    = lane >> 4;

    const int bh = blockIdx.x >> 6;
    const int q0 = (blockIdx.x & 63) << 4;

    const float* Qb = Q + (size_t)bh * Sn * Dn + (size_t)q0 * Dn;
    const float* Kb = K + (size_t)bh * Sn * Dn;
    const float* Vb = V + (size_t)bh * Sn * Dn;
    const int*   Mb = M + (size_t)bh * Sn * Sn + (size_t)q0 * Sn;
    float*       Ab = attnO + (size_t)bh * Sn * Sn + (size_t)q0 * Sn;
    float*       Cb = ctxO  + (size_t)bh * Sn * Dn + (size_t)q0 * Dn;

    v8s qh0, qh1, ql0, ql1;
    {
        const float* qp = Qb + fr * Dn + (g << 3);
        float x0[8], x1[8];
        *(v4f*)&x0[0] = *(const v4f*)qp;
        *(v4f*)&x0[4] = *(const v4f*)(qp + 4);
        *(v4f*)&x1[0] = *(const v4f*)(qp + 32);
        *(v4f*)&x1[4] = *(const v4f*)(qp + 36);
        #pragma unroll
        for (int i = 0; i < 8; ++i) {
            unsigned short hh, ll;
            split2(x0[i], hh, ll); qh0[i] = (short)hh; ql0[i] = (short)ll;
            split2(x1[i], hh, ll); qh1[i] = (short)hh; ql1[i] = (short)ll;
        }
    }

    const int srow = tid >> 4;
    const int sc4  = (tid & 15) << 2;

    const int* mp = Mb + (size_t)fr * Sn + (w << 4) + (g << 2);
    v4i mv = *(const v4i*)mp;

    v4f ka[4];
    #pragma unroll
    for (int i = 0; i < 4; ++i)
        ka[i] = *(const v4f*)(Kb + (size_t)(srow + (i << 4)) * Dn + sc4);

    float rs = 0.f;

    for (int kt = 0; kt < 16; ++kt) {
        __syncthreads();
        v4f kb[4];
        if (kt < 15) {
            const float* kn = Kb + (size_t)((kt + 1) << 6) * Dn;
            #pragma unroll
            for (int i = 0; i < 4; ++i)
                kb[i] = *(const v4f*)(kn + (size_t)(srow + (i << 4)) * Dn + sc4);
        }
        v4i mnext = mv;
        if (kt < 15) mnext = *(const v4i*)(mp + ((kt + 1) << 6));

        #pragma unroll
        for (int i = 0; i < 4; ++i) {
            const int row = srow + (i << 4);
            ushort4 hv, lv;
            split2(ka[i][0], hv.x, lv.x); split2(ka[i][1], hv.y, lv.y);
            split2(ka[i][2], hv.z, lv.z); split2(ka[i][3], hv.w, lv.w);
            *(ushort4*)&Khi[row][sc4] = hv;
            *(ushort4*)&Klo[row][sc4] = lv;
        }
        __syncthreads();

        const int krow = (w << 4) + fr;
        const v8s kh0 = *(const v8s*)&Khi[krow][(g << 3)];
        const v8s kh1 = *(const v8s*)&Khi[krow][32 + (g << 3)];
        const v8s kl0 = *(const v8s*)&Klo[krow][(g << 3)];
        const v8s kl1 = *(const v8s*)&Klo[krow][32 + (g << 3)];

        v4f acc = {0.f, 0.f, 0.f, 0.f};
        acc = __builtin_amdgcn_mfma_f32_16x16x32_bf16(kh0, qh0, acc, 0, 0, 0);
        acc = __builtin_amdgcn_mfma_f32_16x16x32_bf16(kh1, qh1, acc, 0, 0, 0);
        acc = __builtin_amdgcn_mfma_f32_16x16x32_bf16(kl0, qh0, acc, 0, 0, 0);
        acc = __builtin_amdgcn_mfma_f32_16x16x32_bf16(kl1, qh1, acc, 0, 0, 0);
        acc = __builtin_amdgcn_mfma_f32_16x16x32_bf16(kh0, ql0, acc, 0, 0, 0);
        acc = __builtin_amdgcn_mfma_f32_16x16x32_bf16(kh1, ql1, acc, 0, 0, 0);

        const float e0 = mv[0] ? 1.0f : __expf(acc[0]);
        const float e1 = mv[1] ? 1.0f : __expf(acc[1]);
        const float e2 = mv[2] ? 1.0f : __expf(acc[2]);
        const float e3 = mv[3] ? 1.0f : __expf(acc[3]);
        rs += (e0 + e1) + (e2 + e3);
        ushort4 pk;
        pk.x = f2bf(e0); pk.y = f2bf(e1); pk.z = f2bf(e2); pk.w = f2bf(e3);
        *(ushort4*)&Ph[fr][(kt << 6) + (w << 4) + (g << 2)] = pk;

        mv = mnext;
        #pragma unroll
        for (int i = 0; i < 4; ++i) ka[i] = kb[i];
    }

    rs += __shfl_xor(rs, 16);
    rs += __shfl_xor(rs, 32);
    if (g == 0) rsumW[w][fr] = rs;
    __syncthreads();
    if (tid < 16) {
        const float s = rsumW[0][tid] + rsumW[1][tid] + rsumW[2][tid] + rsumW[3][tid];
        invL[tid] = 1.0f / s;
    }
    __syncthreads();

    const int dcol = (w << 4) + fr;
    v4f va[4];
    #pragma unroll
    for (int i = 0; i < 4; ++i)
        va[i] = *(const v4f*)(Vb + (size_t)(srow + (i << 4)) * Dn + sc4);

    v4f accp = {0.f, 0.f, 0.f, 0.f};
    for (int kt = 0; kt < 16; ++kt) {
        __syncthreads();
        v4f vb[4];
        if (kt < 15) {
            const float* vn = Vb + (size_t)((kt + 1) << 6) * Dn;
            #pragma unroll
            for (int i = 0; i < 4; ++i)
                vb[i] = *(const v4f*)(vn + (size_t)(srow + (i << 4)) * Dn + sc4);
        }
        #pragma unroll
        for (int i = 0; i < 4; ++i) {
            const int row = srow + (i << 4);
            Vt[sc4 + 0][row] = f2bf(va[i][0]);
            Vt[sc4 + 1][row] = f2bf(va[i][1]);
            Vt[sc4 + 2][row] = f2bf(va[i][2]);
            Vt[sc4 + 3][row] = f2bf(va[i][3]);
        }
        __syncthreads();

        #pragma unroll
        for (int c = 0; c < 2; ++c) {
            const int kc = (kt << 6) + (c << 5);
            const v8s a = *(const v8s*)&Ph[fr][kc + (g << 3)];
            const v8s b = *(const v8s*)&Vt[dcol][(c << 5) + (g << 3)];
            accp = __builtin_amdgcn_mfma_f32_16x16x32_bf16(a, b, accp, 0, 0, 0);
        }
        #pragma unroll
        for (int i = 0; i < 4; ++i) va[i] = vb[i];
    }
    #pragma unroll
    for (int r = 0; r < 4; ++r) {
        const int q = (g << 2) + r;
        Cb[(size_t)q * Dn + dcol] = accp[r] * invL[q];
    }

    {
        const int qq = tid >> 4, ii = tid & 15;
        const float inv = invL[qq];
        float* arow = Ab + (size_t)qq * Sn;
        #pragma unroll
        for (int c = 0; c < 16; ++c) {
            const int k0 = (c << 6) + (ii << 2);
            const ushort4 p = *(const ushort4*)&Ph[qq][k0];
            v4f o;
            o[0] = bf2f(p.x) * inv; o[1] = bf2f(p.y) * inv;
            o[2] = bf2f(p.z) * inv; o[3] = bf2f(p.w) * inv;
            *(v4f*)(arow + k0) = o;
        }
    }
}

extern "C" void kernel_launch(void* const* d_in, const int* in_sizes, int n_in,
                              void* d_out, int out_size, void* d_ws, size_t ws_size,
                              hipStream_t stream) {
    const float* Q    = (const float*)d_in[0];
    const float* K    = (const float*)d_in[1];
    const float* V    = (const float*)d_in[2];
    const int*   mask = (const int*)d_in[3];

    float* ctx  = (float*)d_out;                           // (B,H,S,D)
    float* attn = (float*)d_out + (size_t)128 * Sn * Dn;   // (B,H,S,S)

    const size_t NELEM = (size_t)128 * Sn * Dn;            // 8,388,608
    const size_t MWORDS = (size_t)128 * Sn * 16;           // 2,097,152 u64
    const size_t NEED  = NELEM * 6 + MWORDS * 8;           // KF+VF 50.3MB + bits 16.8MB

    if (ws_size >= NEED) {
        unsigned short* KF = (unsigned short*)d_ws;        // hi/lo frag-interleaved
        unsigned short* VF = KF + NELEM * 2;               // V^T frag-interleaved
        unsigned long long* MWp = (unsigned long long*)((char*)d_ws + NELEM * 6);
        prep_all<<<6144, 256, 0, stream>>>(K, V, mask, KF, VF, MWp);
        fused_attn_c<<<128 * 64, 256, 0, stream>>>(KF, VF, Q, MWp, attn, ctx);
    } else {
        fused_attn_fb<<<128 * 64, 256, 0, stream>>>(Q, K, V, mask, attn, ctx);
    }
}

// Round 15
// 295.240 us; speedup vs baseline: 1.2638x; 1.0203x over previous
//
#include <hip/hip_runtime.h>

#define Sn 1024
#define Dn 64
#define PH_LD 1032   // ushorts/row: 516 dw ≡ 4 (mod 32) -> conflict-min (verified r10)
#define K_LD 72
#define V_LD 72

typedef short v8s __attribute__((ext_vector_type(8)));
typedef unsigned short v8u __attribute__((ext_vector_type(8)));
typedef float v4f __attribute__((ext_vector_type(4)));
typedef int   v4i __attribute__((ext_vector_type(4)));

#define LGKM0()  asm volatile("s_waitcnt lgkmcnt(0)" ::: "memory")
#define SBAR()   do { asm volatile("" ::: "memory"); __builtin_amdgcn_s_barrier(); \
                      __builtin_amdgcn_sched_barrier(0); } while (0)

__device__ __forceinline__ unsigned short f2bf(float x) {
    union { float f; unsigned u; } v; v.f = x;
    return (unsigned short)((v.u + 0x7FFFu + ((v.u >> 16) & 1u)) >> 16);
}
__device__ __forceinline__ float bf2f(unsigned short h) {
    union { float f; unsigned u; } v; v.u = ((unsigned)h) << 16;
    return v.f;
}
__device__ __forceinline__ void split2(float x, unsigned short& h, unsigned short& l) {
    unsigned short hs = f2bf(x);
    h = hs; l = f2bf(x - bf2f(hs));
}

// ---- prep: K -> fragment-interleaved bf16 hi/lo (r10, proven) ----
__global__ __launch_bounds__(256) void prep_kf(const float* __restrict__ K,
    unsigned short* __restrict__ KF)
{
    const int bh = blockIdx.x >> 4, kt = blockIdx.x & 15;
    const int t = threadIdx.x;
    const int w = t >> 6, lane = t & 63;
    const int fr = lane & 15, g = lane >> 4;
    const float* src = K + (((size_t)(bh << 10) + (kt << 6) + (w << 4) + fr) << 6);
    const v4f a0 = __builtin_nontemporal_load((const v4f*)(src + (g << 3)));
    const v4f a1 = __builtin_nontemporal_load((const v4f*)(src + (g << 3) + 4));
    const v4f b0 = __builtin_nontemporal_load((const v4f*)(src + 32 + (g << 3)));
    const v4f b1 = __builtin_nontemporal_load((const v4f*)(src + 32 + (g << 3) + 4));
    v8u h0, h1, l0, l1;
    #pragma unroll
    for (int j = 0; j < 4; ++j) {
        unsigned short hh, ll;
        split2(a0[j], hh, ll); h0[j] = hh;     l0[j] = ll;
        split2(a1[j], hh, ll); h0[4 + j] = hh; l0[4 + j] = ll;
        split2(b0[j], hh, ll); h1[j] = hh;     l1[j] = ll;
        split2(b1[j], hh, ll); h1[4 + j] = hh; l1[4 + j] = ll;
    }
    unsigned short* dst = KF + ((size_t)bh << 17) + ((size_t)((kt << 2) + w) << 11) + (lane << 3);
    *(v8u*)(dst)        = h0;
    *(v8u*)(dst + 512)  = h1;
    *(v8u*)(dst + 1024) = l0;
    *(v8u*)(dst + 1536) = l1;
}

// ---- prep: V -> fragment-interleaved V^T bf16 (r10, proven) ----
__global__ __launch_bounds__(256) void prep_vf(const float* __restrict__ V,
    unsigned short* __restrict__ VF)
{
    __shared__ float Ts[64][65];
    const int bh = blockIdx.x >> 4, kt = blockIdx.x & 15;
    const int t = threadIdx.x;
    {
        const int r = t >> 2, cs = (t & 3) << 4;
        const float* src = V + ((size_t)bh * Sn + (kt << 6) + r) * Dn + cs;
        const v4f a = __builtin_nontemporal_load((const v4f*)src);
        const v4f b = __builtin_nontemporal_load((const v4f*)src + 1);
        const v4f c = __builtin_nontemporal_load((const v4f*)src + 2);
        const v4f d = __builtin_nontemporal_load((const v4f*)src + 3);
        #pragma unroll
        for (int j = 0; j < 4; ++j) {
            Ts[r][cs + j]      = a[j];
            Ts[r][cs + 4 + j]  = b[j];
            Ts[r][cs + 8 + j]  = c[j];
            Ts[r][cs + 12 + j] = d[j];
        }
    }
    __syncthreads();
    {
        const int w = t >> 6, lane = t & 63;
        const int fr = lane & 15, g = lane >> 4;
        const int d = (w << 4) + fr;
        unsigned short* dst = VF + ((size_t)bh << 16) + ((size_t)((kt << 2) + w) << 10) + (lane << 3);
        v8u o0, o1;
        #pragma unroll
        for (int j = 0; j < 8; ++j) o0[j] = f2bf(Ts[(g << 3) + j][d]);
        #pragma unroll
        for (int j = 0; j < 8; ++j) o1[j] = f2bf(Ts[32 + (g << 3) + j][d]);
        *(v8u*)dst         = o0;
        *(v8u*)(dst + 512) = o1;
    }
}

// ---- prep: mask int32 -> bit-packed u64 words (r10, proven) ----
__global__ __launch_bounds__(256) void prep_m(const int* __restrict__ M,
    unsigned long long* __restrict__ MW)
{
    const int NW = 2097152;
    const int lane = threadIdx.x & 63;
    const int wave = (blockIdx.x << 2) + (threadIdx.x >> 6);
    const int nwaves = gridDim.x << 2;
    for (int w0 = wave << 3; w0 < NW; w0 += nwaves << 3) {
        unsigned long long b[8];
        #pragma unroll
        for (int s = 0; s < 8; ++s) {
            const int v = __builtin_nontemporal_load(&M[((size_t)(w0 + s) << 6) + lane]);
            b[s] = __ballot(v != 0);
        }
        if (lane == 0) {
            ulonglong2* dst = (ulonglong2*)(MW + w0);
            ulonglong2 p0, p1, p2, p3;
            p0.x = b[0]; p0.y = b[1]; p1.x = b[2]; p1.y = b[3];
            p2.x = b[4]; p2.y = b[5]; p3.x = b[6]; p3.y = b[7];
            dst[0] = p0; dst[1] = p1; dst[2] = p2; dst[3] = p3;
        }
    }
}

// ---- fused attention: 16-q tile, 8 waves (short chains), 24 waves/CU ----
// Phase A: wave w owns kt={2w,2w+1}, 8 sub-steps of 16-k each (KF idx kt*4+kk).
// Phase B: wave w owns d-slice (w&3), kt-half (w>>2); pair-reduce via LDS.
// All NT stores LAST (in-order vmcnt: stores never block compute loads).
__global__ __launch_bounds__(512, 6) void fused_attn_h(
    const unsigned short* __restrict__ KFG, const unsigned short* __restrict__ VFG,
    const float* __restrict__ Q, const unsigned long long* __restrict__ MW,
    float* __restrict__ attnO, float* __restrict__ ctxO)
{
    __shared__ unsigned short Ph[16][PH_LD];   // 33,024 B
    __shared__ float rsumW[8][16];
    __shared__ float invL[16];
    __shared__ float pv[4][16][16];            // phase-B pair reduction

    const int tid  = threadIdx.x;
    const int lane = tid & 63;
    const int w    = tid >> 6;     // 0..7
    const int fr   = lane & 15;
    const int g    = lane >> 4;

    // bijective XCD swizzle: all 64 q-blocks of one bh on one XCD
    const int swz = ((blockIdx.x & 7) << 10) + (blockIdx.x >> 3);
    const int bh = swz >> 6;
    const int q0 = (swz & 63) << 4;

    const float* Qb = Q + (size_t)bh * Sn * Dn + (size_t)q0 * Dn;
    float*       Ab = attnO + (size_t)bh * Sn * Sn + (size_t)q0 * Sn;
    float*       Cb = ctxO  + (size_t)bh * Sn * Dn + (size_t)q0 * Dn;
    const unsigned short* KFb = KFG + ((size_t)bh << 17);
    const unsigned short* VFb = VFG + ((size_t)bh << 16);
    const unsigned long long* mwp = MW + ((size_t)bh << 14) + ((size_t)(q0 + fr) << 4);

    // Q B-fragments (per-lane row fr)
    v8s qh0, qh1, ql0, ql1;
    {
        const float* qp = Qb + fr * Dn + (g << 3);
        float x0[8], x1[8];
        *(v4f*)&x0[0] = *(const v4f*)qp;
        *(v4f*)&x0[4] = *(const v4f*)(qp + 4);
        *(v4f*)&x1[0] = *(const v4f*)(qp + 32);
        *(v4f*)&x1[4] = *(const v4f*)(qp + 36);
        #pragma unroll
        for (int i = 0; i < 8; ++i) {
            unsigned short hh, ll;
            split2(x0[i], hh, ll); qh0[i] = (short)hh; ql0[i] = (short)ll;
            split2(x1[i], hh, ll); qh1[i] = (short)hh; ql1[i] = (short)ll;
        }
    }

    // sub-step s (0..7): kt = 2w + (s>>2), kk = s&3
#define LDKS(s, h0_, h1_, l0_, l1_) do {                                           \
        const int _kt = (w << 1) + ((s) >> 2);                                     \
        const unsigned short* _p = KFb + ((size_t)(((_kt) << 2) + ((s) & 3)) << 11) + (lane << 3); \
        h0_ = *(const v8s*)_p;          h1_ = *(const v8s*)(_p + 512);             \
        l0_ = *(const v8s*)(_p + 1024); l1_ = *(const v8s*)(_p + 1536);            \
    } while (0)

#define STEPA(h0_, h1_, l0_, l1_, mwv, s) do {                                     \
        v4f acc = {0.f, 0.f, 0.f, 0.f};                                            \
        __builtin_amdgcn_s_setprio(1);                                             \
        acc = __builtin_amdgcn_mfma_f32_16x16x32_bf16(h0_, qh0, acc, 0, 0, 0);     \
        acc = __builtin_amdgcn_mfma_f32_16x16x32_bf16(h1_, qh1, acc, 0, 0, 0);     \
        acc = __builtin_amdgcn_mfma_f32_16x16x32_bf16(l0_, qh0, acc, 0, 0, 0);     \
        acc = __builtin_amdgcn_mfma_f32_16x16x32_bf16(l1_, qh1, acc, 0, 0, 0);     \
        acc = __builtin_amdgcn_mfma_f32_16x16x32_bf16(h0_, ql0, acc, 0, 0, 0);     \
        acc = __builtin_amdgcn_mfma_f32_16x16x32_bf16(h1_, ql1, acc, 0, 0, 0);     \
        __builtin_amdgcn_s_setprio(0);                                             \
        const int _sh = (((s) & 3) << 4) + (g << 2);                               \
        const unsigned mb = (unsigned)((mwv) >> _sh);                              \
        const float e0 = (mb & 1u) ? 1.0f : __expf(acc[0]);                        \
        const float e1 = (mb & 2u) ? 1.0f : __expf(acc[1]);                        \
        const float e2 = (mb & 4u) ? 1.0f : __expf(acc[2]);                        \
        const float e3 = (mb & 8u) ? 1.0f : __expf(acc[3]);                        \
        rs += (e0 + e1) + (e2 + e3);                                               \
        ushort4 pk;                                                                \
        pk.x = f2bf(e0); pk.y = f2bf(e1); pk.z = f2bf(e2); pk.w = f2bf(e3);        \
        const int _kc = (((w << 1) + ((s) >> 2)) << 6) + (((s) & 3) << 4) + (g << 2); \
        *(ushort4*)&Ph[fr][_kc] = pk;                                              \
    } while (0)

    float rs = 0.f;

    // ---- Phase A: 8 sub-steps, barrier-free, depth-2 slots ----
    {
        v8s h0[2], h1[2], l0[2], l1[2];
        unsigned long long mk[2];
        LDKS(0, h0[0], h1[0], l0[0], l1[0]);
        LDKS(1, h0[1], h1[1], l0[1], l1[1]);
        mk[0] = mwp[(w << 1)];
        mk[1] = mwp[(w << 1) + 1];
        #pragma unroll
        for (int s = 0; s < 8; ++s) {
            STEPA(h0[s & 1], h1[s & 1], l0[s & 1], l1[s & 1], mk[s >> 2], s);
            if (s + 2 < 8) LDKS(s + 2, h0[s & 1], h1[s & 1], l0[s & 1], l1[s & 1]);
        }
    }

    // ---- row-sum reduce across 8 waves ----
    rs += __shfl_xor(rs, 16);
    rs += __shfl_xor(rs, 32);
    if (g == 0) rsumW[w][fr] = rs;
    __builtin_amdgcn_sched_barrier(0);
    LGKM0();
    SBAR();                                   // Ph + rsumW visible
    if (tid < 16) {
        float s = 0.f;
        #pragma unroll
        for (int ww = 0; ww < 8; ++ww) s += rsumW[ww][tid];
        invL[tid] = 1.0f / s;
    }
    __builtin_amdgcn_sched_barrier(0);
    LGKM0();
    SBAR();                                   // invL visible

    // ---- Phase B: wave w -> d-slice (w&3), kt-half (w>>2) ----
    const int dsl  = w & 3;
    const int half = w >> 2;
    const int ktb  = half << 3;
    const int dcol = (dsl << 4) + fr;

#define LDV(kt, v0_, v1_) do {                                                     \
        const unsigned short* _p = VFb + ((size_t)(((kt) << 2) + dsl) << 10) + (lane << 3); \
        v0_ = *(const v8s*)_p;  v1_ = *(const v8s*)(_p + 512);                     \
    } while (0)

#define STEPB(v0_, v1_, kt) do {                                                   \
        const v8s a0 = *(const v8s*)&Ph[fr][((kt) << 6) + (g << 3)];               \
        const v8s a1 = *(const v8s*)&Ph[fr][((kt) << 6) + 32 + (g << 3)];          \
        __builtin_amdgcn_s_setprio(1);                                             \
        accp = __builtin_amdgcn_mfma_f32_16x16x32_bf16(a0, v0_, accp, 0, 0, 0);    \
        accp = __builtin_amdgcn_mfma_f32_16x16x32_bf16(a1, v1_, accp, 0, 0, 0);    \
        __builtin_amdgcn_s_setprio(0);                                             \
    } while (0)

    v4f accp = {0.f, 0.f, 0.f, 0.f};
    {
        v8s v0s[2], v1s[2];
        LDV(ktb + 0, v0s[0], v1s[0]);
        LDV(ktb + 1, v0s[1], v1s[1]);
        #pragma unroll
        for (int i = 0; i < 8; ++i) {
            STEPB(v0s[i & 1], v1s[i & 1], ktb + i);
            if (i + 2 < 8) LDV(ktb + i + 2, v0s[i & 1], v1s[i & 1]);
        }
    }

    // pair-reduce: upper half writes partials, lower half combines + stores ctx
    if (half) {
        #pragma unroll
        for (int r = 0; r < 4; ++r) pv[dsl][(g << 2) + r][fr] = accp[r];
    }
    __builtin_amdgcn_sched_barrier(0);
    LGKM0();
    SBAR();
    if (!half) {
        #pragma unroll
        for (int r = 0; r < 4; ++r) {
            const int q = (g << 2) + r;
            const float o = (accp[r] + pv[dsl][q][fr]) * invL[q];
            __builtin_nontemporal_store(o, &Cb[(size_t)q * Dn + dcol]);
        }
    }

    // ---- attn write LAST (store drain overlaps other blocks' compute) ----
    {
        const int qq = tid >> 5, ii = tid & 31;
        const float inv = invL[qq];
        float* arow = Ab + (size_t)qq * Sn;
        #pragma unroll
        for (int c = 0; c < 8; ++c) {
            const int k0 = (c << 7) + (ii << 2);
            const ushort4 p = *(const ushort4*)&Ph[qq][k0];
            v4f o;
            o[0] = bf2f(p.x) * inv; o[1] = bf2f(p.y) * inv;
            o[2] = bf2f(p.z) * inv; o[3] = bf2f(p.w) * inv;
            __builtin_nontemporal_store(o, (v4f*)(arow + k0));
        }
    }
#undef LDKS
#undef STEPA
#undef LDV
#undef STEPB
}

// ---------------- fallback (round-3 kernel, in-kernel split) ----------------
__global__ __launch_bounds__(256, 3) void fused_attn_fb(
    const float* __restrict__ Q, const float* __restrict__ K,
    const float* __restrict__ V, const int* __restrict__ M,
    float* __restrict__ attnO, float* __restrict__ ctxO)
{
    __shared__ unsigned short Ph[16][1048];
    __shared__ __align__(16) unsigned short Kraw[2 * 64 * K_LD];
    __shared__ float rsumW[4][16];
    __shared__ float invL[16];

    unsigned short (*Khi)[K_LD] = (unsigned short (*)[K_LD])Kraw;
    unsigned short (*Klo)[K_LD] = (unsigned short (*)[K_LD])(Kraw + 64 * K_LD);
    unsigned short (*Vt)[V_LD]  = (unsigned short (*)[V_LD])Kraw;

    const int tid  = threadIdx.x;
    const int lane = tid & 63;
    const int w    = tid >> 6;
    const int fr   = lane & 15;
    const int g    = lane >> 4;

    const int bh = blockIdx.x >> 6;
    const int q0 = (blockIdx.x & 63) << 4;

    const float* Qb = Q + (size_t)bh * Sn * Dn + (size_t)q0 * Dn;
    const float* Kb = K + (size_t)bh * Sn * Dn;
    const float* Vb = V + (size_t)bh * Sn * Dn;
    const int*   Mb = M + (size_t)bh * Sn * Sn + (size_t)q0 * Sn;
    float*       Ab = attnO + (size_t)bh * Sn * Sn + (size_t)q0 * Sn;
    float*       Cb = ctxO  + (size_t)bh * Sn * Dn + (size_t)q0 * Dn;

    v8s qh0, qh1, ql0, ql1;
    {
        const float* qp = Qb + fr * Dn + (g << 3);
        float x0[8], x1[8];
        *(v4f*)&x0[0] = *(const v4f*)qp;
        *(v4f*)&x0[4] = *(const v4f*)(qp + 4);
        *(v4f*)&x1[0] = *(const v4f*)(qp + 32);
        *(v4f*)&x1[4] = *(const v4f*)(qp + 36);
        #pragma unroll
        for (int i = 0; i < 8; ++i) {
            unsigned short hh, ll;
            split2(x0[i], hh, ll); qh0[i] = (short)hh; ql0[i] = (short)ll;
            split2(x1[i], hh, ll); qh1[i] = (short)hh; ql1[i] = (short)ll;
        }
    }

    const int srow = tid >> 4;
    const int sc4  = (tid & 15) << 2;

    const int* mp = Mb + (size_t)fr * Sn + (w << 4) + (g << 2);
    v4i mv = *(const v4i*)mp;

    v4f ka[4];
    #pragma unroll
    for (int i = 0; i < 4; ++i)
        ka[i] = *(const v4f*)(Kb + (size_t)(srow + (i << 4)) * Dn + sc4);

    float rs = 0.f;

    for (int kt = 0; kt < 16; ++kt) {
        __syncthreads();
        v4f kb[4];
        if (kt < 15) {
            const float* kn = Kb + (size_t)((kt + 1) << 6) * Dn;
            #pragma unroll
            for (int i = 0; i < 4; ++i)
                kb[i] = *(const v4f*)(kn + (size_t)(srow + (i << 4)) * Dn + sc4);
        }
        v4i mnext = mv;
        if (kt < 15) mnext = *(const v4i*)(mp + ((kt + 1) << 6));

        #pragma unroll
        for (int i = 0; i < 4; ++i) {
            const int row = srow + (i << 4);
            ushort4 hv, lv;
            split2(ka[i][0], hv.x, lv.x); split2(ka[i][1], hv.y, lv.y);
            split2(ka[i][2], hv.z, lv.z); split2(ka[i][3], hv.w, lv.w);
            *(ushort4*)&Khi[row][sc4] = hv;
            *(ushort4*)&Klo[row][sc4] = lv;
        }
        __syncthreads();

        const int krow = (w << 4) + fr;
        const v8s kh0 = *(const v8s*)&Khi[krow][(g << 3)];
        const v8s kh1 = *(const v8s*)&Khi[krow][32 + (g << 3)];
        const v8s kl0 = *(const v8s*)&Klo[krow][(g << 3)];
        const v8s kl1 = *(const v8s*)&Klo[krow][32 + (g << 3)];

        v4f acc = {0.f, 0.f, 0.f, 0.f};
        acc = __builtin_amdgcn_mfma_f32_16x16x32_bf16(kh0, qh0, acc, 0, 0, 0);
        acc = __builtin_amdgcn_mfma_f32_16x16x32_bf16(kh1, qh1, acc, 0, 0, 0);
        acc = __builtin_amdgcn_mfma_f32_16x16x32_bf16(kl0, qh0, acc, 0, 0, 0);
        acc = __builtin_amdgcn_mfma_f32_16x16x32_bf16(kl1, qh1, acc, 0, 0, 0);
        acc = __builtin_amdgcn_mfma_f32_16x16x32_bf16(kh0, ql0, acc, 0, 0, 0);
        acc = __builtin_amdgcn_mfma_f32_16x16x32_bf16(kh1, ql1, acc, 0, 0, 0);

        const float e0 = mv[0] ? 1.0f : __expf(acc[0]);
        const float e1 = mv[1] ? 1.0f : __expf(acc[1]);
        const float e2 = mv[2] ? 1.0f : __expf(acc[2]);
        const float e3 = mv[3] ? 1.0f : __expf(acc[3]);
        rs += (e0 + e1) + (e2 + e3);
        ushort4 pk;
        pk.x = f2bf(e0); pk.y = f2bf(e1); pk.z = f2bf(e2); pk.w = f2bf(e3);
        *(ushort4*)&Ph[fr][(kt << 6) + (w << 4) + (g << 2)] = pk;

        mv = mnext;
        #pragma unroll
        for (int i = 0; i < 4; ++i) ka[i] = kb[i];
    }

    rs += __shfl_xor(rs, 16);
    rs += __shfl_xor(rs, 32);
    if (g == 0) rsumW[w][fr] = rs;
    __syncthreads();
    if (tid < 16) {
        const float s = rsumW[0][tid] + rsumW[1][tid] + rsumW[2][tid] + rsumW[3][tid];
        invL[tid] = 1.0f / s;
    }
    __syncthreads();

    const int dcol = (w << 4) + fr;
    v4f va[4];
    #pragma unroll
    for (int i = 0; i < 4; ++i)
        va[i] = *(const v4f*)(Vb + (size_t)(srow + (i << 4)) * Dn + sc4);

    v4f accp = {0.f, 0.f, 0.f, 0.f};
    for (int kt = 0; kt < 16; ++kt) {
        __syncthreads();
        v4f vb[4];
        if (kt < 15) {
            const float* vn = Vb + (size_t)((kt + 1) << 6) * Dn;
            #pragma unroll
            for (int i = 0; i < 4; ++i)
                vb[i] = *(const v4f*)(vn + (size_t)(srow + (i << 4)) * Dn + sc4);
        }
        #pragma unroll
        for (int i = 0; i < 4; ++i) {
            const int row = srow + (i << 4);
            Vt[sc4 + 0][row] = f2bf(va[i][0]);
            Vt[sc4 + 1][row] = f2bf(va[i][1]);
            Vt[sc4 + 2][row] = f2bf(va[i][2]);
            Vt[sc4 + 3][row] = f2bf(va[i][3]);
        }
        __syncthreads();

        #pragma unroll
        for (int c = 0; c < 2; ++c) {
            const int kc = (kt << 6) + (c << 5);
            const v8s a = *(const v8s*)&Ph[fr][kc + (g << 3)];
            const v8s b = *(const v8s*)&Vt[dcol][(c << 5) + (g << 3)];
            accp = __builtin_amdgcn_mfma_f32_16x16x32_bf16(a, b, accp, 0, 0, 0);
        }
        #pragma unroll
        for (int i = 0; i < 4; ++i) va[i] = vb[i];
    }
    #pragma unroll
    for (int r = 0; r < 4; ++r) {
        const int q = (g << 2) + r;
        Cb[(size_t)q * Dn + dcol] = accp[r] * invL[q];
    }

    {
        const int qq = tid >> 4, ii = tid & 15;
        const float inv = invL[qq];
        float* arow = Ab + (size_t)qq * Sn;
        #pragma unroll
        for (int c = 0; c < 16; ++c) {
            const int k0 = (c << 6) + (ii << 2);
            const ushort4 p = *(const ushort4*)&Ph[qq][k0];
            v4f o;
            o[0] = bf2f(p.x) * inv; o[1] = bf2f(p.y) * inv;
            o[2] = bf2f(p.z) * inv; o[3] = bf2f(p.w) * inv;
            *(v4f*)(arow + k0) = o;
        }
    }
}

extern "C" void kernel_launch(void* const* d_in, const int* in_sizes, int n_in,
                              void* d_out, int out_size, void* d_ws, size_t ws_size,
                              hipStream_t stream) {
    const float* Q    = (const float*)d_in[0];
    const float* K    = (const float*)d_in[1];
    const float* V    = (const float*)d_in[2];
    const int*   mask = (const int*)d_in[3];

    float* ctx  = (float*)d_out;                           // (B,H,S,D)
    float* attn = (float*)d_out + (size_t)128 * Sn * Dn;   // (B,H,S,S)

    const size_t NELEM = (size_t)128 * Sn * Dn;            // 8,388,608
    const size_t MWORDS = (size_t)128 * Sn * 16;           // 2,097,152 u64
    const size_t NEED  = NELEM * 6 + MWORDS * 8;           // KF+VF 50.3MB + bits 16.8MB

    if (ws_size >= NEED) {
        unsigned short* KF = (unsigned short*)d_ws;        // hi/lo frag-interleaved
        unsigned short* VF = KF + NELEM * 2;               // V^T frag-interleaved
        unsigned long long* MWp = (unsigned long long*)((char*)d_ws + NELEM * 6);
        prep_kf<<<2048, 256, 0, stream>>>(K, KF);
        prep_vf<<<2048, 256, 0, stream>>>(V, VF);
        prep_m<<<2048, 256, 0, stream>>>(mask, MWp);
        fused_attn_h<<<128 * 64, 512, 0, stream>>>(KF, VF, Q, MWp, attn, ctx);
    } else {
        fused_attn_fb<<<128 * 64, 256, 0, stream>>>(Q, K, V, mask, attn, ctx);
    }
}

// Round 16
// 263.512 us; speedup vs baseline: 1.4160x; 1.1204x over previous
//
#include <hip/hip_runtime.h>

#define Sn 1024
#define Dn 64
#define PH_LD 1032   // ushorts/row: 516 dw ≡ 4 (mod 32) -> conflict-min (verified r10)
#define K_LD 72
#define V_LD 72

typedef short v8s __attribute__((ext_vector_type(8)));
typedef unsigned short v8u __attribute__((ext_vector_type(8)));
typedef _Float16 v8h __attribute__((ext_vector_type(8)));
typedef float v4f __attribute__((ext_vector_type(4)));
typedef int   v4i __attribute__((ext_vector_type(4)));

#define LGKM0()  asm volatile("s_waitcnt lgkmcnt(0)" ::: "memory")
#define SBAR()   do { asm volatile("" ::: "memory"); __builtin_amdgcn_s_barrier(); \
                      __builtin_amdgcn_sched_barrier(0); } while (0)

__device__ __forceinline__ unsigned short f2bf(float x) {
    union { float f; unsigned u; } v; v.f = x;
    return (unsigned short)((v.u + 0x7FFFu + ((v.u >> 16) & 1u)) >> 16);
}
__device__ __forceinline__ float bf2f(unsigned short h) {
    union { float f; unsigned u; } v; v.u = ((unsigned)h) << 16;
    return v.f;
}
__device__ __forceinline__ void split2(float x, unsigned short& h, unsigned short& l) {
    unsigned short hs = f2bf(x);
    h = hs; l = f2bf(x - bf2f(hs));
}

// ---- prep: K -> fragment-interleaved fp16 ----
// KF[bh][kt][w][c][lane][8] halves; c=0: d=g*8.., c=1: d=32+g*8..
// Fused fragment load = 64 lanes x 16B contiguous (1KB, fully coalesced).
__global__ __launch_bounds__(256) void prep_kh(const float* __restrict__ K,
    unsigned short* __restrict__ KF)
{
    const int bh = blockIdx.x >> 4, kt = blockIdx.x & 15;
    const int t = threadIdx.x;
    const int w = t >> 6, lane = t & 63;
    const int fr = lane & 15, g = lane >> 4;
    const float* src = K + (((size_t)(bh << 10) + (kt << 6) + (w << 4) + fr) << 6);
    const v4f a0 = __builtin_nontemporal_load((const v4f*)(src + (g << 3)));
    const v4f a1 = __builtin_nontemporal_load((const v4f*)(src + (g << 3) + 4));
    const v4f b0 = __builtin_nontemporal_load((const v4f*)(src + 32 + (g << 3)));
    const v4f b1 = __builtin_nontemporal_load((const v4f*)(src + 32 + (g << 3) + 4));
    v8h c0, c1;
    #pragma unroll
    for (int j = 0; j < 4; ++j) {
        c0[j] = (_Float16)a0[j]; c0[4 + j] = (_Float16)a1[j];
        c1[j] = (_Float16)b0[j]; c1[4 + j] = (_Float16)b1[j];
    }
    unsigned short* dst = KF + ((size_t)bh << 16) + ((size_t)((kt << 2) + w) << 10) + (lane << 3);
    *(v8h*)(dst)       = c0;
    *(v8h*)(dst + 512) = c1;
}

// ---- prep: V -> fragment-interleaved V^T bf16 (r10, proven) ----
__global__ __launch_bounds__(256) void prep_vf(const float* __restrict__ V,
    unsigned short* __restrict__ VF)
{
    __shared__ float Ts[64][65];
    const int bh = blockIdx.x >> 4, kt = blockIdx.x & 15;
    const int t = threadIdx.x;
    {
        const int r = t >> 2, cs = (t & 3) << 4;
        const float* src = V + ((size_t)bh * Sn + (kt << 6) + r) * Dn + cs;
        const v4f a = __builtin_nontemporal_load((const v4f*)src);
        const v4f b = __builtin_nontemporal_load((const v4f*)src + 1);
        const v4f c = __builtin_nontemporal_load((const v4f*)src + 2);
        const v4f d = __builtin_nontemporal_load((const v4f*)src + 3);
        #pragma unroll
        for (int j = 0; j < 4; ++j) {
            Ts[r][cs + j]      = a[j];
            Ts[r][cs + 4 + j]  = b[j];
            Ts[r][cs + 8 + j]  = c[j];
            Ts[r][cs + 12 + j] = d[j];
        }
    }
    __syncthreads();
    {
        const int w = t >> 6, lane = t & 63;
        const int fr = lane & 15, g = lane >> 4;
        const int d = (w << 4) + fr;
        unsigned short* dst = VF + ((size_t)bh << 16) + ((size_t)((kt << 2) + w) << 10) + (lane << 3);
        v8u o0, o1;
        #pragma unroll
        for (int j = 0; j < 8; ++j) o0[j] = f2bf(Ts[(g << 3) + j][d]);
        #pragma unroll
        for (int j = 0; j < 8; ++j) o1[j] = f2bf(Ts[32 + (g << 3) + j][d]);
        *(v8u*)dst         = o0;
        *(v8u*)(dst + 512) = o1;
    }
}

// ---- prep: mask int32 -> bit-packed u64 words (r10, proven) ----
__global__ __launch_bounds__(256) void prep_m(const int* __restrict__ M,
    unsigned long long* __restrict__ MW)
{
    const int NW = 2097152;
    const int lane = threadIdx.x & 63;
    const int wave = (blockIdx.x << 2) + (threadIdx.x >> 6);
    const int nwaves = gridDim.x << 2;
    for (int w0 = wave << 3; w0 < NW; w0 += nwaves << 3) {
        unsigned long long b[8];
        #pragma unroll
        for (int s = 0; s < 8; ++s) {
            const int v = __builtin_nontemporal_load(&M[((size_t)(w0 + s) << 6) + lane]);
            b[s] = __ballot(v != 0);
        }
        if (lane == 0) {
            ulonglong2* dst = (ulonglong2*)(MW + w0);
            ulonglong2 p0, p1, p2, p3;
            p0.x = b[0]; p0.y = b[1]; p1.x = b[2]; p1.y = b[3];
            p2.x = b[4]; p2.y = b[5]; p3.x = b[6]; p3.y = b[7];
            dst[0] = p0; dst[1] = p1; dst[2] = p2; dst[3] = p3;
        }
    }
}

// ---- fused attention: r10 structure, fp16 single-term QK^T (2 MFMA/step) ----
// Block: 16 q-rows, 4 waves, 4 blocks/CU (LDS = Ph only, 33 KB). Barrier-free
// phases; K frag = one coalesced 1KB load (half of r10's bytes); depth-4
// prefetch. P stays bf16 (exp can exceed fp16 range). Phase B = r10 verbatim.
__global__ __launch_bounds__(256, 4) void fused_attn_f(
    const unsigned short* __restrict__ KFG, const unsigned short* __restrict__ VFG,
    const float* __restrict__ Q, const unsigned long long* __restrict__ MW,
    float* __restrict__ attnO, float* __restrict__ ctxO)
{
    __shared__ unsigned short Ph[16][PH_LD];
    __shared__ float rsumW[4][16];
    __shared__ float invL[16];

    const int tid  = threadIdx.x;
    const int lane = tid & 63;
    const int w    = tid >> 6;
    const int fr   = lane & 15;
    const int g    = lane >> 4;

    // bijective XCD swizzle: all 64 q-blocks of one bh on one XCD
    const int swz = ((blockIdx.x & 7) << 10) + (blockIdx.x >> 3);
    const int bh = swz >> 6;
    const int q0 = (swz & 63) << 4;

    const float* Qb = Q + (size_t)bh * Sn * Dn + (size_t)q0 * Dn;
    float*       Ab = attnO + (size_t)bh * Sn * Sn + (size_t)q0 * Sn;
    float*       Cb = ctxO  + (size_t)bh * Sn * Dn + (size_t)q0 * Dn;
    const unsigned short* KFb = KFG + ((size_t)bh << 16);
    const unsigned short* VFb = VFG + ((size_t)bh << 16);
    const unsigned long long* mwp = MW + ((size_t)bh << 14) + ((size_t)(q0 + fr) << 4);

    // Q B-fragments, fp16 single (once per block)
    v8h qf0, qf1;
    {
        const float* qp = Qb + fr * Dn + (g << 3);
        const v4f x0a = *(const v4f*)qp;
        const v4f x0b = *(const v4f*)(qp + 4);
        const v4f x1a = *(const v4f*)(qp + 32);
        const v4f x1b = *(const v4f*)(qp + 36);
        #pragma unroll
        for (int j = 0; j < 4; ++j) {
            qf0[j] = (_Float16)x0a[j]; qf0[4 + j] = (_Float16)x0b[j];
            qf1[j] = (_Float16)x1a[j]; qf1[4 + j] = (_Float16)x1b[j];
        }
    }

    const int sh = (w << 4) + (g << 2);

#define LDK(kt, k0_, k1_) do {                                                     \
        const unsigned short* _p = KFb + ((size_t)(((kt) << 2) + w) << 10) + (lane << 3); \
        k0_ = *(const v8h*)_p;  k1_ = *(const v8h*)(_p + 512);                     \
    } while (0)

#define STEPA(k0_, k1_, mwv, kt) do {                                              \
        v4f acc = {0.f, 0.f, 0.f, 0.f};                                            \
        __builtin_amdgcn_s_setprio(1);                                             \
        acc = __builtin_amdgcn_mfma_f32_16x16x32_f16(k0_, qf0, acc, 0, 0, 0);      \
        acc = __builtin_amdgcn_mfma_f32_16x16x32_f16(k1_, qf1, acc, 0, 0, 0);      \
        __builtin_amdgcn_s_setprio(0);                                             \
        const unsigned mb = (unsigned)((mwv) >> sh);                               \
        const float e0 = (mb & 1u) ? 1.0f : __expf(acc[0]);                        \
        const float e1 = (mb & 2u) ? 1.0f : __expf(acc[1]);                        \
        const float e2 = (mb & 4u) ? 1.0f : __expf(acc[2]);                        \
        const float e3 = (mb & 8u) ? 1.0f : __expf(acc[3]);                        \
        rs += (e0 + e1) + (e2 + e3);                                               \
        ushort4 pk;                                                                \
        pk.x = f2bf(e0); pk.y = f2bf(e1); pk.z = f2bf(e2); pk.w = f2bf(e3);        \
        *(ushort4*)&Ph[fr][((kt) << 6) + (w << 4) + (g << 2)] = pk;                \
    } while (0)

    float rs = 0.f;

    // ---- Phase A: barrier-free; depth-4 K slots + depth-4 mask ring ----
    {
        v8h k0s[4], k1s[4];
        unsigned long long mk[4];
        LDK(0, k0s[0], k1s[0]);
        LDK(1, k0s[1], k1s[1]);
        LDK(2, k0s[2], k1s[2]);
        LDK(3, k0s[3], k1s[3]);
        mk[0] = mwp[0]; mk[1] = mwp[1]; mk[2] = mwp[2]; mk[3] = mwp[3];
        #pragma unroll
        for (int kt = 0; kt < 16; ++kt) {
            STEPA(k0s[kt & 3], k1s[kt & 3], mk[kt & 3], kt);
            if (kt + 4 < 16) {
                LDK(kt + 4, k0s[kt & 3], k1s[kt & 3]);
                mk[kt & 3] = mwp[kt + 4];
            }
        }
    }

    // ---- row-sum reduce (only barriers; raw, no vmcnt drain) ----
    rs += __shfl_xor(rs, 16);
    rs += __shfl_xor(rs, 32);
    if (g == 0) rsumW[w][fr] = rs;
    __builtin_amdgcn_sched_barrier(0);
    LGKM0();
    SBAR();
    if (tid < 16) {
        const float s = rsumW[0][tid] + rsumW[1][tid] + rsumW[2][tid] + rsumW[3][tid];
        invL[tid] = 1.0f / s;
    }
    __builtin_amdgcn_sched_barrier(0);
    LGKM0();
    SBAR();

#define LDV(kt, v0_, v1_) do {                                                     \
        const unsigned short* _p = VFb + ((size_t)(((kt) << 2) + w) << 10) + (lane << 3); \
        v0_ = *(const v8s*)_p;  v1_ = *(const v8s*)(_p + 512);                     \
    } while (0)

#define STEPB(v0_, v1_, kt) do {                                                   \
        const v8s a0 = *(const v8s*)&Ph[fr][((kt) << 6) + (g << 3)];               \
        const v8s a1 = *(const v8s*)&Ph[fr][((kt) << 6) + 32 + (g << 3)];          \
        __builtin_amdgcn_s_setprio(1);                                             \
        accp = __builtin_amdgcn_mfma_f32_16x16x32_bf16(a0, v0_, accp, 0, 0, 0);    \
        accp = __builtin_amdgcn_mfma_f32_16x16x32_bf16(a1, v1_, accp, 0, 0, 0);    \
        __builtin_amdgcn_s_setprio(0);                                             \
    } while (0)

    // Issue first V frag loads BEFORE the attn store burst (in-order vmcnt:
    // loads before stores -> Phase B never waits on the store stream).
    v8s va0, va1, vb0, vb1;
    LDV(0, va0, va1);
    LDV(1, vb0, vb1);

    // ---- write normalized attn (NT burst drains under Phase B) ----
    {
        const int qq = tid >> 4, ii = tid & 15;
        const float inv = invL[qq];
        float* arow = Ab + (size_t)qq * Sn;
        #pragma unroll
        for (int c = 0; c < 16; ++c) {
            const int k0 = (c << 6) + (ii << 2);
            const ushort4 p = *(const ushort4*)&Ph[qq][k0];
            v4f o;
            o[0] = bf2f(p.x) * inv; o[1] = bf2f(p.y) * inv;
            o[2] = bf2f(p.z) * inv; o[3] = bf2f(p.w) * inv;
            __builtin_nontemporal_store(o, (v4f*)(arow + k0));
        }
    }

    // ---- Phase B: barrier-free, coalesced V frags (r10 verbatim) ----
    const int dcol = (w << 4) + fr;
    v4f accp = {0.f, 0.f, 0.f, 0.f};
    for (int kt = 0; kt < 16; kt += 2) {
        const int k2 = (kt + 2 < 16) ? kt + 2 : kt;
        const int k3 = (kt + 3 < 16) ? kt + 3 : kt;
        v8s vc0, vc1, vd0, vd1;
        LDV(k2, vc0, vc1);
        LDV(k3, vd0, vd1);
        STEPB(va0, va1, kt);
        STEPB(vb0, vb1, kt + 1);
        va0 = vc0; va1 = vc1;
        vb0 = vd0; vb1 = vd1;
    }
    #pragma unroll
    for (int r = 0; r < 4; ++r) {
        const int q = (g << 2) + r;
        __builtin_nontemporal_store(accp[r] * invL[q], &Cb[(size_t)q * Dn + dcol]);
    }
#undef LDK
#undef STEPA
#undef LDV
#undef STEPB
}

// ---------------- fallback (round-3 kernel, in-kernel split) ----------------
__global__ __launch_bounds__(256, 3) void fused_attn_fb(
    const float* __restrict__ Q, const float* __restrict__ K,
    const float* __restrict__ V, const int* __restrict__ M,
    float* __restrict__ attnO, float* __restrict__ ctxO)
{
    __shared__ unsigned short Ph[16][1048];
    __shared__ __align__(16) unsigned short Kraw[2 * 64 * K_LD];
    __shared__ float rsumW[4][16];
    __shared__ float invL[16];

    unsigned short (*Khi)[K_LD] = (unsigned short (*)[K_LD])Kraw;
    unsigned short (*Klo)[K_LD] = (unsigned short (*)[K_LD])(Kraw + 64 * K_LD);
    unsigned short (*Vt)[V_LD]  = (unsigned short (*)[V_LD])Kraw;

    const int tid  = threadIdx.x;
    const int lane = tid & 63;
    const int w    = tid >> 6;
    const int fr   = lane & 15;
    const int g    = lane >> 4;

    const int bh = blockIdx.x >> 6;
    const int q0 = (blockIdx.x & 63) << 4;

    const float* Qb = Q + (size_t)bh * Sn * Dn + (size_t)q0 * Dn;
    const float* Kb = K + (size_t)bh * Sn * Dn;
    const float* Vb = V + (size_t)bh * Sn * Dn;
    const int*   Mb = M + (size_t)bh * Sn * Sn + (size_t)q0 * Sn;
    float*       Ab = attnO + (size_t)bh * Sn * Sn + (size_t)q0 * Sn;
    float*       Cb = ctxO  + (size_t)bh * Sn * Dn + (size_t)q0 * Dn;

    v8s qh0, qh1, ql0, ql1;
    {
        const float* qp = Qb + fr * Dn + (g << 3);
        float x0[8], x1[8];
        *(v4f*)&x0[0] = *(const v4f*)qp;
        *(v4f*)&x0[4] = *(const v4f*)(qp + 4);
        *(v4f*)&x1[0] = *(const v4f*)(qp + 32);
        *(v4f*)&x1[4] = *(const v4f*)(qp + 36);
        #pragma unroll
        for (int i = 0; i < 8; ++i) {
            unsigned short hh, ll;
            split2(x0[i], hh, ll); qh0[i] = (short)hh; ql0[i] = (short)ll;
            split2(x1[i], hh, ll); qh1[i] = (short)hh; ql1[i] = (short)ll;
        }
    }

    const int srow = tid >> 4;
    const int sc4  = (tid & 15) << 2;

    const int* mp = Mb + (size_t)fr * Sn + (w << 4) + (g << 2);
    v4i mv = *(const v4i*)mp;

    v4f ka[4];
    #pragma unroll
    for (int i = 0; i < 4; ++i)
        ka[i] = *(const v4f*)(Kb + (size_t)(srow + (i << 4)) * Dn + sc4);

    float rs = 0.f;

    for (int kt = 0; kt < 16; ++kt) {
        __syncthreads();
        v4f kb[4];
        if (kt < 15) {
            const float* kn = Kb + (size_t)((kt + 1) << 6) * Dn;
            #pragma unroll
            for (int i = 0; i < 4; ++i)
                kb[i] = *(const v4f*)(kn + (size_t)(srow + (i << 4)) * Dn + sc4);
        }
        v4i mnext = mv;
        if (kt < 15) mnext = *(const v4i*)(mp + ((kt + 1) << 6));

        #pragma unroll
        for (int i = 0; i < 4; ++i) {
            const int row = srow + (i << 4);
            ushort4 hv, lv;
            split2(ka[i][0], hv.x, lv.x); split2(ka[i][1], hv.y, lv.y);
            split2(ka[i][2], hv.z, lv.z); split2(ka[i][3], hv.w, lv.w);
            *(ushort4*)&Khi[row][sc4] = hv;
            *(ushort4*)&Klo[row][sc4] = lv;
        }
        __syncthreads();

        const int krow = (w << 4) + fr;
        const v8s kh0 = *(const v8s*)&Khi[krow][(g << 3)];
        const v8s kh1 = *(const v8s*)&Khi[krow][32 + (g << 3)];
        const v8s kl0 = *(const v8s*)&Klo[krow][(g << 3)];
        const v8s kl1 = *(const v8s*)&Klo[krow][32 + (g << 3)];

        v4f acc = {0.f, 0.f, 0.f, 0.f};
        acc = __builtin_amdgcn_mfma_f32_16x16x32_bf16(kh0, qh0, acc, 0, 0, 0);
        acc = __builtin_amdgcn_mfma_f32_16x16x32_bf16(kh1, qh1, acc, 0, 0, 0);
        acc = __builtin_amdgcn_mfma_f32_16x16x32_bf16(kl0, qh0, acc, 0, 0, 0);
        acc = __builtin_amdgcn_mfma_f32_16x16x32_bf16(kl1, qh1, acc, 0, 0, 0);
        acc = __builtin_amdgcn_mfma_f32_16x16x32_bf16(kh0, ql0, acc, 0, 0, 0);
        acc = __builtin_amdgcn_mfma_f32_16x16x32_bf16(kh1, ql1, acc, 0, 0, 0);

        const float e0 = mv[0] ? 1.0f : __expf(acc[0]);
        const float e1 = mv[1] ? 1.0f : __expf(acc[1]);
        const float e2 = mv[2] ? 1.0f : __expf(acc[2]);
        const float e3 = mv[3] ? 1.0f : __expf(acc[3]);
        rs += (e0 + e1) + (e2 + e3);
        ushort4 pk;
        pk.x = f2bf(e0); pk.y = f2bf(e1); pk.z = f2bf(e2); pk.w = f2bf(e3);
        *(ushort4*)&Ph[fr][(kt << 6) + (w << 4) + (g << 2)] = pk;

        mv = mnext;
        #pragma unroll
        for (int i = 0; i < 4; ++i) ka[i] = kb[i];
    }

    rs += __shfl_xor(rs, 16);
    rs += __shfl_xor(rs, 32);
    if (g == 0) rsumW[w][fr] = rs;
    __syncthreads();
    if (tid < 16) {
        const float s = rsumW[0][tid] + rsumW[1][tid] + rsumW[2][tid] + rsumW[3][tid];
        invL[tid] = 1.0f / s;
    }
    __syncthreads();

    const int dcol = (w << 4) + fr;
    v4f va[4];
    #pragma unroll
    for (int i = 0; i < 4; ++i)
        va[i] = *(const v4f*)(Vb + (size_t)(srow + (i << 4)) * Dn + sc4);

    v4f accp = {0.f, 0.f, 0.f, 0.f};
    for (int kt = 0; kt < 16; ++kt) {
        __syncthreads();
        v4f vb[4];
        if (kt < 15) {
            const float* vn = Vb + (size_t)((kt + 1) << 6) * Dn;
            #pragma unroll
            for (int i = 0; i < 4; ++i)
                vb[i] = *(const v4f*)(vn + (size_t)(srow + (i << 4)) * Dn + sc4);
        }
        #pragma unroll
        for (int i = 0; i < 4; ++i) {
            const int row = srow + (i << 4);
            Vt[sc4 + 0][row] = f2bf(va[i][0]);
            Vt[sc4 + 1][row] = f2bf(va[i][1]);
            Vt[sc4 + 2][row] = f2bf(va[i][2]);
            Vt[sc4 + 3][row] = f2bf(va[i][3]);
        }
        __syncthreads();

        #pragma unroll
        for (int c = 0; c < 2; ++c) {
            const int kc = (kt << 6) + (c << 5);
            const v8s a = *(const v8s*)&Ph[fr][kc + (g << 3)];
            const v8s b = *(const v8s*)&Vt[dcol][(c << 5) + (g << 3)];
            accp = __builtin_amdgcn_mfma_f32_16x16x32_bf16(a, b, accp, 0, 0, 0);
        }
        #pragma unroll
        for (int i = 0; i < 4; ++i) va[i] = vb[i];
    }
    #pragma unroll
    for (int r = 0; r < 4; ++r) {
        const int q = (g << 2) + r;
        Cb[(size_t)q * Dn + dcol] = accp[r] * invL[q];
    }

    {
        const int qq = tid >> 4, ii = tid & 15;
        const float inv = invL[qq];
        float* arow = Ab + (size_t)qq * Sn;
        #pragma unroll
        for (int c = 0; c < 16; ++c) {
            const int k0 = (c << 6) + (ii << 2);
            const ushort4 p = *(const ushort4*)&Ph[qq][k0];
            v4f o;
            o[0] = bf2f(p.x) * inv; o[1] = bf2f(p.y) * inv;
            o[2] = bf2f(p.z) * inv; o[3] = bf2f(p.w) * inv;
            *(v4f*)(arow + k0) = o;
        }
    }
}

extern "C" void kernel_launch(void* const* d_in, const int* in_sizes, int n_in,
                              void* d_out, int out_size, void* d_ws, size_t ws_size,
                              hipStream_t stream) {
    const float* Q    = (const float*)d_in[0];
    const float* K    = (const float*)d_in[1];
    const float* V    = (const float*)d_in[2];
    const int*   mask = (const int*)d_in[3];

    float* ctx  = (float*)d_out;                           // (B,H,S,D)
    float* attn = (float*)d_out + (size_t)128 * Sn * Dn;   // (B,H,S,S)

    const size_t NELEM = (size_t)128 * Sn * Dn;            // 8,388,608
    const size_t MWORDS = (size_t)128 * Sn * 16;           // 2,097,152 u64
    const size_t NEED  = NELEM * 4 + MWORDS * 8;           // KF 16.8 + VF 16.8 + bits 16.8 MB

    if (ws_size >= NEED) {
        unsigned short* KF = (unsigned short*)d_ws;        // fp16 frag-interleaved
        unsigned short* VF = KF + NELEM;                   // V^T bf16 frag-interleaved
        unsigned long long* MWp = (unsigned long long*)((char*)d_ws + NELEM * 4);
        prep_kh<<<2048, 256, 0, stream>>>(K, KF);
        prep_vf<<<2048, 256, 0, stream>>>(V, VF);
        prep_m<<<2048, 256, 0, stream>>>(mask, MWp);
        fused_attn_f<<<128 * 64, 256, 0, stream>>>(KF, VF, Q, MWp, attn, ctx);
    } else {
        fused_attn_fb<<<128 * 64, 256, 0, stream>>>(Q, K, V, mask, attn, ctx);
    }
}